// Round 8
// baseline (360.591 us; speedup 1.0000x reference)
//
#include <hip/hip_runtime.h>
#include <cstdint>
#include <cstddef>

typedef unsigned short u16;
typedef __bf16 bf16x8 __attribute__((ext_vector_type(8)));
typedef float f32x4 __attribute__((ext_vector_type(4)));
typedef unsigned short u16x8 __attribute__((ext_vector_type(8)));

#define SEQ 4096
#define HID 2048
#define NH 16
#define HD 128
#define WIN 1024

__device__ __forceinline__ float bf2f(u16 u) {
  union { unsigned int i; float f; } v; v.i = ((unsigned int)u) << 16; return v.f;
}
__device__ __forceinline__ u16 f2bf(float f) {
  union { float f; unsigned int i; } v; v.f = f;
  unsigned int r = v.i + 0x7FFFu + ((v.i >> 16) & 1u);
  return (u16)(r >> 16);
}
__device__ __forceinline__ u16 f2bf_rne(float f) {
  union { __bf16 b; u16 u; } v; v.b = (__bf16)f; return v.u;
}
__device__ __forceinline__ unsigned pk2(float lo, float hi) {
  return (unsigned)f2bf_rne(lo) | ((unsigned)f2bf_rne(hi) << 16);
}
__device__ __forceinline__ float exp2a(float x) {
  float r; asm("v_exp_f32 %0, %1" : "=v"(r) : "v"(x)); return r;
}
// XOR swizzle within a tile whose rows are (1<<L2R) bytes. Involution; keeps 16B alignment.
template<int L2R>
__device__ __forceinline__ unsigned swz(unsigned o) { return o ^ (((o >> L2R) & 7u) << 4); }

__device__ __forceinline__ void gload_lds16(const u16* g, u16* l) {
  __builtin_amdgcn_global_load_lds((const __attribute__((address_space(1))) void*)g,
                                   (__attribute__((address_space(3))) void*)l, 16, 0, 0);
}

// ---------------- elementwise prep ----------------

__global__ void cast_f32_bf16(const float* __restrict__ in, u16* __restrict__ out, int n4) {
  int i = blockIdx.x * blockDim.x + threadIdx.x;
  if (i < n4) {
    float4 v = ((const float4*)in)[i];
    union { u16 u[4]; unsigned long long ll; } r;
    r.u[0] = f2bf(v.x); r.u[1] = f2bf(v.y); r.u[2] = f2bf(v.z); r.u[3] = f2bf(v.w);
    ((unsigned long long*)out)[i] = r.ll;
  }
}

// 4 weight matrices (HID x HID, f32, row-major) -> bf16 transposed, one launch
__global__ void transpose_cast4(const float* __restrict__ w0, const float* __restrict__ w1,
                                const float* __restrict__ w2, const float* __restrict__ w3,
                                u16* __restrict__ o0, u16* __restrict__ o1,
                                u16* __restrict__ o2, u16* __restrict__ o3) {
  __shared__ float t[32][33];
  const float* W = (blockIdx.z == 0) ? w0 : (blockIdx.z == 1) ? w1 : (blockIdx.z == 2) ? w2 : w3;
  u16* Wt = (blockIdx.z == 0) ? o0 : (blockIdx.z == 1) ? o1 : (blockIdx.z == 2) ? o2 : o3;
  const int tx = threadIdx.x & 31, ty = threadIdx.x >> 5;  // ty 0..7
  const int x0 = blockIdx.x * 32, y0 = blockIdx.y * 32;
#pragma unroll
  for (int i = 0; i < 4; ++i)
    t[ty + i * 8][tx] = W[(size_t)(y0 + ty + i * 8) * HID + x0 + tx];
  __syncthreads();
#pragma unroll
  for (int i = 0; i < 4; ++i)
    Wt[(size_t)(x0 + ty + i * 8) * HID + y0 + tx] = f2bf(t[tx][ty + i * 8]);
}

__global__ void rope_table(float* __restrict__ ctab, float* __restrict__ stab) {
  int idx = blockIdx.x * blockDim.x + threadIdx.x;  // SEQ*64
  int pos = idx >> 6, i = idx & 63;
  float invf = expf(-(float)i * 0.14391156831212787f);  // ln(10000)/64
  float ang = (float)pos * invf;
  float s, c;
  sincosf(ang, &s, &c);
  ctab[idx] = c; stab[idx] = s;
}

// ---------------- GEMM core: drain-free counted-vmcnt pipeline ----------------
// C[M,N] = A[M,K]*Bt[N,K]^T, bf16 in, f32 acc. 128x128 tile, BK=64, 8 waves (512 thr):
// 4 M-waves (wr = wv>>1, 32 rows each) x 2 N-groups (wc = wv&1) with interleaved
// fragment map nmap = {2wc, 2wc+1, 2wc+4, 2wc+5} so each thread holds cols i AND i+64
// (RoPE fusion preserved). 4 LDS buffers (128KB, 1 block/CU), depth-3 prefetch,
// ONE barrier per K-tile, vmcnt(8) steady (never 0 mid-loop): the prefetch stays in
// flight across the barrier -- removes the syncthreads vmcnt(0) drain of the m97 form.
// Per-thread loads/tile = 4 (2 A + 2 B chunks).
//
// Safety argument (per-tile, buf = kt&3):
//  - vmcnt(8): newest 8 = tiles kt+1,kt+2 -> tile kt's 4 loads landed (all waves do this
//    before the barrier => whole tile kt is in LDS after the barrier).
//  - lgkmcnt(0) before barrier: this wave's tile kt-1 ds_reads retired => after barrier,
//    buffer (kt+3)&3 == (kt-1)&3 is reusable; stage(kt+3) is issued only after barrier.

template<bool OUT_F32, bool ROPE>
__device__ __forceinline__ void gemm_body(const u16* __restrict__ A, const u16* __restrict__ Bt,
                                          void* __restrict__ C, int brow, int bcol, bool do_rope,
                                          const float* __restrict__ ctab,
                                          const float* __restrict__ stab,
                                          u16 (&ldsA)[4][8192], u16 (&ldsB)[4][8192]) {
  const int tid = threadIdx.x;
  const int lane = tid & 63;
  const int wv = tid >> 6;          // 0..7
  const int wr = wv >> 1;           // 0..3 : rows wr*32..wr*32+31
  const int wc = wv & 1;            // 0..1 : col fragments nmap
  const int g = lane >> 4, c = lane & 15;
  const int K = HID, N = HID;
  const int nmap0 = 2 * wc;         // fragments {nmap0, nmap0+1, nmap0+4, nmap0+5}

  const f32x4 zero = {0.f, 0.f, 0.f, 0.f};
  f32x4 acc[2][4];
#pragma unroll
  for (int m = 0; m < 2; ++m)
#pragma unroll
    for (int j = 0; j < 4; ++j) acc[m][j] = zero;

  auto stage = [&](int buf, int kt) {
    const int k0 = kt * 64;
#pragma unroll
    for (int i = 0; i < 2; ++i) {
      unsigned idx = (unsigned)(i * 512 + tid);   // 0..1023 16B-chunks per matrix
      unsigned o = idx * 16u;
      unsigned r = o >> 7;                        // tile row (128B rows: 64 bf16)
      unsigned cb = swz<7>(o) & 127u;             // pre-swizzled col-bytes
      const size_t gcol = (size_t)k0 + (cb >> 1);
      gload_lds16(A + (size_t)(brow + r) * K + gcol, &ldsA[buf][idx * 8]);
      gload_lds16(Bt + (size_t)(bcol + r) * K + gcol, &ldsB[buf][idx * 8]);
    }
  };

  const int nt = K / 64;  // 32
  stage(0, 0); stage(1, 1); stage(2, 2);

  int bc = 0;
  for (int kt = 0; kt < nt; ++kt) {
    if (kt + 2 < nt)       asm volatile("s_waitcnt vmcnt(8)" ::: "memory");
    else if (kt + 1 < nt)  asm volatile("s_waitcnt vmcnt(4)" ::: "memory");
    else                   asm volatile("s_waitcnt vmcnt(0)" ::: "memory");
    asm volatile("s_waitcnt lgkmcnt(0)" ::: "memory");
    __builtin_amdgcn_s_barrier();
    asm volatile("" ::: "memory");
    __builtin_amdgcn_sched_barrier(0);

    if (kt + 3 < nt) {
      int bs = bc + 3; if (bs >= 4) bs -= 4;
      stage(bs, kt + 3);
    }

    __builtin_amdgcn_s_setprio(1);
#pragma unroll
    for (int s = 0; s < 2; ++s) {
      const unsigned kb = (unsigned)(s * 64 + g * 16);
      bf16x8 af[2], bfv[4];
#pragma unroll
      for (int m = 0; m < 2; ++m) {
        unsigned row = (unsigned)(wr * 32 + m * 16 + c);
        af[m] = *(const bf16x8*)((const char*)&ldsA[bc][0] + swz<7>(row * 128 + kb));
      }
#pragma unroll
      for (int j = 0; j < 4; ++j) {
        const int n = nmap0 + ((j & 1) ? 1 : 0) + ((j >> 1) ? 4 : 0);
        unsigned row = (unsigned)(n * 16 + c);
        bfv[j] = *(const bf16x8*)((const char*)&ldsB[bc][0] + swz<7>(row * 128 + kb));
      }
#pragma unroll
      for (int m = 0; m < 2; ++m)
#pragma unroll
        for (int j = 0; j < 4; ++j)
          acc[m][j] = __builtin_amdgcn_mfma_f32_16x16x32_bf16(af[m], bfv[j], acc[m][j], 0, 0, 0);
    }
    __builtin_amdgcn_s_setprio(0);

    ++bc; if (bc == 4) bc = 0;
  }

  // epilogue: acc[m][j] covers row = brow + wr*32 + m*16 + g*4 + r,
  //           col = bcol + (nmap0 + (j&1) + (j>>1)*4)*16 + c.
  // j and j+2 are 64 cols apart -> rotary pairs in-register.
  if (ROPE && do_rope) {
#pragma unroll
    for (int m = 0; m < 2; ++m) {
      const int rbase = brow + wr * 32 + m * 16 + g * 4;
#pragma unroll
      for (int r = 0; r < 4; ++r) {
        const int pos = rbase + r;
        const float* cp = ctab + (size_t)pos * 64;
        const float* sp = stab + (size_t)pos * 64;
        u16* crow = (u16*)C + (size_t)pos * N + bcol;
#pragma unroll
        for (int jj = 0; jj < 2; ++jj) {
          const int i = wc * 32 + jj * 16 + c;
          const float x1 = acc[m][jj][r], x2 = acc[m][jj + 2][r];
          const float co = cp[i], si = sp[i];
          crow[i] = f2bf(x1 * co - x2 * si);
          crow[i + 64] = f2bf(x2 * co + x1 * si);
        }
      }
    }
  } else {
#pragma unroll
    for (int m = 0; m < 2; ++m) {
      const int rbase = brow + wr * 32 + m * 16 + g * 4;
#pragma unroll
      for (int r = 0; r < 4; ++r) {
#pragma unroll
        for (int j = 0; j < 4; ++j) {
          const int n = nmap0 + (j & 1) + ((j >> 1) ? 4 : 0);
          const size_t idx = (size_t)(rbase + r) * N + bcol + n * 16 + c;
          if (OUT_F32) ((float*)C)[idx] = acc[m][j][r];
          else ((u16*)C)[idx] = f2bf(acc[m][j][r]);
        }
      }
    }
  }
}

__global__ __launch_bounds__(512, 2) void gemm_qkv_kernel(
    const u16* __restrict__ X, const u16* __restrict__ Wqt, const u16* __restrict__ Wkt,
    const u16* __restrict__ Wvt, u16* __restrict__ Qo, u16* __restrict__ Ko, u16* __restrict__ Vo,
    const float* __restrict__ ctab, const float* __restrict__ stab) {
  __shared__ u16 ldsA[4][8192];  // 64KB
  __shared__ u16 ldsB[4][8192];  // 64KB
  // T1 bijective XCD swizzle: 1536 blocks = 8 * 192
  int flat = (blockIdx.z * 32 + blockIdx.y) * 16 + blockIdx.x;
  int nf = (flat & 7) * 192 + (flat >> 3);
  int bx = nf & 15, by = (nf >> 4) & 31, bz = nf >> 9;
  const u16* Bt = (bz == 0) ? Wqt : (bz == 1) ? Wkt : Wvt;
  u16* Cp = (bz == 0) ? Qo : (bz == 1) ? Ko : Vo;
  gemm_body<false, true>(X, Bt, Cp, by * 128, bx * 128, bz < 2, ctab, stab, ldsA, ldsB);
}

__global__ __launch_bounds__(512, 2) void gemm_out_kernel(
    const u16* __restrict__ Ob, const u16* __restrict__ Wot, float* __restrict__ out) {
  __shared__ u16 ldsA[4][8192];
  __shared__ u16 ldsB[4][8192];
  // 512 blocks = 8 * 64
  int flat = blockIdx.y * 16 + blockIdx.x;
  int nf = (flat & 7) * 64 + (flat >> 3);
  int bx = nf & 15, by = nf >> 4;
  gemm_body<true, false>(Ob, Wot, out, by * 128, bx * 128, false, nullptr, nullptr, ldsA, ldsB);
}

// ---------------- windowed flash attention: swapped QK^T, in-register softmax (R7, frozen) ----------------

__global__ __launch_bounds__(256, 3) void attn_kernel(
    const u16* __restrict__ Q, const u16* __restrict__ K,
    const u16* __restrict__ V, u16* __restrict__ O) {
  __shared__ u16 k_lds[2][8192];   // [64 keys(pi-rows)][128 d] swz<8> (256B rows), dbuf 32KB
  __shared__ u16 vt_lds[8192];     // V^T [128 d][64 keys] xor-swizzled, single      16KB

  const int lane = threadIdx.x & 63;
  const int wv = threadIdx.x >> 6;
  const int g = lane >> 4;   // 0..3
  const int c = lane & 15;

  // T1: chunked swizzle so one XCD sees contiguous q-blocks of the same head
  int flat = blockIdx.y * 64 + blockIdx.x;       // 1024 = 8 * 128
  int nf = (flat & 7) * 128 + (flat >> 3);
  const int q0 = (nf & 63) * 64;
  const int h = nf >> 6;
  const int qw = q0 + wv * 16;
  const int qpos = qw + c;       // this lane's q row

  // ---- stage Q via k_lds[0] (linear rows), read qf (B-operand layout) ----
#pragma unroll
  for (int i = 0; i < 4; ++i) {
    unsigned o = ((unsigned)(wv * 4 + i) * 64 + (unsigned)lane) * 16u;
    unsigned r = o >> 8;
    unsigned cb = swz<8>(o) & 255u;
    gload_lds16(Q + (size_t)(q0 + r) * HID + h * HD + (cb >> 1), &k_lds[0][(wv * 4 + i) * 512]);
  }
  __syncthreads();
  bf16x8 qf[4];
#pragma unroll
  for (int s = 0; s < 4; ++s) {
    unsigned row = wv * 16 + c;
    qf[s] = *(const bf16x8*)((const char*)&k_lds[0][0] + swz<8>(row * 256 + s * 64 + g * 16));
  }
  __syncthreads();

  auto stageK = [&](int buf, int t0) {
#pragma unroll
    for (int i = 0; i < 4; ++i) {
      unsigned o = ((unsigned)(wv * 4 + i) * 64 + (unsigned)lane) * 16u;
      unsigned r = o >> 8;  // LDS row 0..63
      // pi-inverse: key bits [r5, r3, r2, r4, r1, r0]
      unsigned key = (r & 0x23u) | ((r & 0x0Cu) << 1) | ((r & 0x10u) >> 2);
      unsigned cb = swz<8>(o) & 255u;
      gload_lds16(K + (size_t)(t0 + (int)key) * HID + h * HD + (cb >> 1),
                  &k_lds[buf][(wv * 4 + i) * 512]);
    }
  };
  u16x8 vr[4];
  auto loadV = [&](int t0) {
    const u16x8* src = (const u16x8*)(V + (size_t)(t0 + lane) * HID + h * HD + wv * 32);
#pragma unroll
    for (int it = 0; it < 4; ++it) vr[it] = src[it];
  };
  auto writeVT = [&]() {
#pragma unroll
    for (int it = 0; it < 4; ++it)
#pragma unroll
      for (int j = 0; j < 8; ++j) {
        const int d = wv * 32 + it * 8 + j;
        vt_lds[d * 64 + (lane ^ ((d & 7) << 3))] = vr[it][j];
      }
  };

  const int t_start = (q0 >= WIN) ? (q0 - WIN) : 0;

  // ---- prologue: tile t_start ----
  loadV(t_start);
  stageK(0, t_start);
  __syncthreads();           // drains vm (K + V loads) + rendezvous
  writeVT();
  __syncthreads();           // VT visible

  const f32x4 zero = {0.f, 0.f, 0.f, 0.f};
  float mrow = -1e30f, lrow = 0.f;
  f32x4 oacc[8];
#pragma unroll
  for (int d = 0; d < 8; ++d) oacc[d] = zero;

  const float scale2 = 0.12751743f;  // (1/sqrt(128)) * log2(e)
  int b = 0;

  for (int t0 = t_start; t0 <= q0; t0 += 64) {
    const bool has_next = (t0 + 64 <= q0);
    if (has_next) {
      loadV(t0 + 64);        // issue V first (oldest; vmcnt(4) below waits only these)
      stageK(b ^ 1, t0 + 64);
    }

    // S^T = K Q (swapped): sa[kf] rows = key-slot g*4+r, col = q = c
    f32x4 sa[4];
#pragma unroll
    for (int kf = 0; kf < 4; ++kf) sa[kf] = zero;
    __builtin_amdgcn_s_setprio(1);
#pragma unroll
    for (int s = 0; s < 4; ++s) {
#pragma unroll
      for (int kf = 0; kf < 4; ++kf) {
        unsigned row = kf * 16 + c;
        bf16x8 kb = *(const bf16x8*)((const char*)&k_lds[b][0] + swz<8>(row * 256 + s * 64 + g * 16));
        sa[kf] = __builtin_amdgcn_mfma_f32_16x16x32_bf16(kb, qf[s], sa[kf], 0, 0, 0);
      }
    }
    __builtin_amdgcn_s_setprio(0);

    // semantic key of sa[kf][r]: t0 + (kf>>1)*32 + g*8 + (kf&1)*4 + r
    const bool diag = (t0 == q0);
    const bool lowm = (q0 >= WIN) && (t0 == t_start);
    if (diag) {
#pragma unroll
      for (int kf = 0; kf < 4; ++kf) {
        const int kbase = t0 + (kf >> 1) * 32 + g * 8 + (kf & 1) * 4;
#pragma unroll
        for (int r = 0; r < 4; ++r) {
          float x = sa[kf][r] * scale2;
          sa[kf][r] = (kbase + r <= qpos) ? x : -1e30f;
        }
      }
    } else if (lowm) {
#pragma unroll
      for (int kf = 0; kf < 4; ++kf) {
        const int kbase = t0 + (kf >> 1) * 32 + g * 8 + (kf & 1) * 4;
#pragma unroll
        for (int r = 0; r < 4; ++r) {
          float x = sa[kf][r] * scale2;
          sa[kf][r] = (kbase + r > qpos - WIN) ? x : -1e30f;
        }
      }
    } else {
#pragma unroll
      for (int kf = 0; kf < 4; ++kf)
#pragma unroll
        for (int r = 0; r < 4; ++r) sa[kf][r] *= scale2;
    }

    // row max: in-lane 16 + cross-g
    float tmax = -3e38f;
#pragma unroll
    for (int kf = 0; kf < 4; ++kf)
#pragma unroll
      for (int r = 0; r < 4; ++r) tmax = fmaxf(tmax, sa[kf][r]);
    tmax = fmaxf(tmax, __shfl_xor(tmax, 16));
    tmax = fmaxf(tmax, __shfl_xor(tmax, 32));

    // T13 defer-rescale
    if (!__all((int)(tmax <= mrow + 8.f))) {
      const float mn = fmaxf(mrow, tmax);
      const float al = exp2a(mrow - mn);
      mrow = mn;
      lrow *= al;
      float alo[4];
#pragma unroll
      for (int r = 0; r < 4; ++r) alo[r] = __shfl(al, (lane & 48) | (g * 4 + r));
#pragma unroll
      for (int df = 0; df < 8; ++df)
#pragma unroll
        for (int r = 0; r < 4; ++r) oacc[df][r] *= alo[r];
    }

    // P = exp2(S - m); row-sum
    float rs = 0.f;
    if (diag || lowm) {
#pragma unroll
      for (int kf = 0; kf < 4; ++kf)
#pragma unroll
        for (int r = 0; r < 4; ++r) {
          const float x = sa[kf][r];
          const float p = (x < -1e29f) ? 0.f : exp2a(x - mrow);
          sa[kf][r] = p; rs += p;
        }
    } else {
#pragma unroll
      for (int kf = 0; kf < 4; ++kf)
#pragma unroll
        for (int r = 0; r < 4; ++r) {
          const float p = exp2a(sa[kf][r] - mrow);
          sa[kf][r] = p; rs += p;
        }
    }
    rs += __shfl_xor(rs, 16);
    rs += __shfl_xor(rs, 32);
    lrow += rs;

    // pa from OWN registers (pi-permutation makes P lane-local in A-layout)
    union { bf16x8 v; unsigned u[4]; } pa0, pa1;
    pa0.u[0] = pk2(sa[0][0], sa[0][1]); pa0.u[1] = pk2(sa[0][2], sa[0][3]);
    pa0.u[2] = pk2(sa[1][0], sa[1][1]); pa0.u[3] = pk2(sa[1][2], sa[1][3]);
    pa1.u[0] = pk2(sa[2][0], sa[2][1]); pa1.u[1] = pk2(sa[2][2], sa[2][3]);
    pa1.u[2] = pk2(sa[3][0], sa[3][1]); pa1.u[3] = pk2(sa[3][2], sa[3][3]);

    // O += P V
    __builtin_amdgcn_s_setprio(1);
#pragma unroll
    for (int s2 = 0; s2 < 2; ++s2) {
      const bf16x8 pa = s2 ? pa1.v : pa0.v;
#pragma unroll
      for (int df = 0; df < 8; ++df) {
        const int row = df * 16 + c;
        const bf16x8 vb = *(const bf16x8*)&vt_lds[row * 64 + ((s2 * 32 + g * 8) ^ ((row & 7) << 3))];
        oacc[df] = __builtin_amdgcn_mfma_f32_16x16x32_bf16(pa, vb, oacc[df], 0, 0, 0);
      }
    }
    __builtin_amdgcn_s_setprio(0);

    // barrier1: all waves' K/VT reads retired -> safe to overwrite VT
    asm volatile("s_waitcnt lgkmcnt(0)" ::: "memory");
    __builtin_amdgcn_s_barrier();

    if (has_next) {
      asm volatile("s_waitcnt vmcnt(4)" ::: "memory");  // V regs landed (K gloads may fly)
      writeVT();
    }
    // barrier2: VT writes visible; K(t+1) landed (issued a full tile ago)
    asm volatile("s_waitcnt vmcnt(0) lgkmcnt(0)" ::: "memory");
    __builtin_amdgcn_s_barrier();
    b ^= 1;
  }

  // output: oacc[df][r] = O[qw + g*4 + r][df*16 + c]; l for that row fetched cross-lane
  float ilo[4];
  const float invl = 1.f / lrow;
#pragma unroll
  for (int r = 0; r < 4; ++r) ilo[r] = __shfl(invl, (lane & 48) | (g * 4 + r));
#pragma unroll
  for (int df = 0; df < 8; ++df)
#pragma unroll
    for (int r = 0; r < 4; ++r) {
      const int row = qw + g * 4 + r;
      const int col = h * HD + df * 16 + c;
      O[(size_t)row * HID + col] = f2bf(oacc[df][r] * ilo[r]);
    }
}

// ---------------- launch ----------------

extern "C" void kernel_launch(void* const* d_in, const int* in_sizes, int n_in,
                              void* d_out, int out_size, void* d_ws, size_t ws_size,
                              hipStream_t stream) {
  const float* hidden = (const float*)d_in[0];
  const float* wq = (const float*)d_in[1];
  const float* wk = (const float*)d_in[2];
  const float* wv = (const float*)d_in[3];
  const float* wo = (const float*)d_in[4];
  float* out = (float*)d_out;

  char* ws = (char*)d_ws;
  u16* Xb  = (u16*)ws;                 ws += (size_t)SEQ * HID * 2;
  u16* Wqt = (u16*)ws;                 ws += (size_t)HID * HID * 2;
  u16* Wkt = (u16*)ws;                 ws += (size_t)HID * HID * 2;
  u16* Wvt = (u16*)ws;                 ws += (size_t)HID * HID * 2;
  u16* Wot = (u16*)ws;                 ws += (size_t)HID * HID * 2;
  u16* Qb  = (u16*)ws;                 ws += (size_t)SEQ * HID * 2;
  u16* Kb  = (u16*)ws;                 ws += (size_t)SEQ * HID * 2;
  u16* Vb  = (u16*)ws;                 ws += (size_t)SEQ * HID * 2;
  u16* Ob  = (u16*)ws;                 ws += (size_t)SEQ * HID * 2;
  float* ctab = (float*)ws;            ws += (size_t)SEQ * 64 * 4;
  float* stab = (float*)ws;            ws += (size_t)SEQ * 64 * 4;

  cast_f32_bf16<<<(SEQ * HID / 4 + 255) / 256, 256, 0, stream>>>(hidden, Xb, SEQ * HID / 4);

  dim3 tg(64, 64, 4);
  transpose_cast4<<<tg, 256, 0, stream>>>(wq, wk, wv, wo, Wqt, Wkt, Wvt, Wot);

  rope_table<<<(SEQ * 64) / 256, 256, 0, stream>>>(ctab, stab);

  dim3 gq(HID / 128, SEQ / 128, 3);
  gemm_qkv_kernel<<<gq, 512, 0, stream>>>(Xb, Wqt, Wkt, Wvt, Qb, Kb, Vb, ctab, stab);

  dim3 ga(SEQ / 64, NH);
  attn_kernel<<<ga, 256, 0, stream>>>(Qb, Kb, Vb, Ob);

  dim3 go(HID / 128, SEQ / 128);
  gemm_out_kernel<<<go, 512, 0, stream>>>(Ob, Wot, out);
}

// Round 9
// 264.733 us; speedup vs baseline: 1.3621x; 1.3621x over previous
//
#include <hip/hip_runtime.h>
#include <cstdint>
#include <cstddef>

typedef unsigned short u16;
typedef __bf16 bf16x8 __attribute__((ext_vector_type(8)));
typedef float f32x4 __attribute__((ext_vector_type(4)));
typedef unsigned short u16x8 __attribute__((ext_vector_type(8)));

#define SEQ 4096
#define HID 2048
#define NH 16
#define HD 128
#define WIN 1024

__device__ __forceinline__ float bf2f(u16 u) {
  union { unsigned int i; float f; } v; v.i = ((unsigned int)u) << 16; return v.f;
}
__device__ __forceinline__ u16 f2bf(float f) {
  union { float f; unsigned int i; } v; v.f = f;
  unsigned int r = v.i + 0x7FFFu + ((v.i >> 16) & 1u);
  return (u16)(r >> 16);
}
__device__ __forceinline__ u16 f2bf_rne(float f) {
  union { __bf16 b; u16 u; } v; v.b = (__bf16)f; return v.u;
}
__device__ __forceinline__ unsigned pk2(float lo, float hi) {
  return (unsigned)f2bf_rne(lo) | ((unsigned)f2bf_rne(hi) << 16);
}
__device__ __forceinline__ float exp2a(float x) {
  float r; asm("v_exp_f32 %0, %1" : "=v"(r) : "v"(x)); return r;
}
// XOR swizzle within a tile whose rows are (1<<L2R) bytes. Involution; keeps 16B alignment.
template<int L2R>
__device__ __forceinline__ unsigned swz(unsigned o) { return o ^ (((o >> L2R) & 7u) << 4); }

__device__ __forceinline__ void gload_lds16(const u16* g, u16* l) {
  __builtin_amdgcn_global_load_lds((const __attribute__((address_space(1))) void*)g,
                                   (__attribute__((address_space(3))) void*)l, 16, 0, 0);
}

// ---------------- elementwise prep ----------------

__global__ void cast_f32_bf16(const float* __restrict__ in, u16* __restrict__ out, int n4) {
  int i = blockIdx.x * blockDim.x + threadIdx.x;
  if (i < n4) {
    float4 v = ((const float4*)in)[i];
    union { u16 u[4]; unsigned long long ll; } r;
    r.u[0] = f2bf(v.x); r.u[1] = f2bf(v.y); r.u[2] = f2bf(v.z); r.u[3] = f2bf(v.w);
    ((unsigned long long*)out)[i] = r.ll;
  }
}

// 4 weight matrices (HID x HID, f32, row-major) -> bf16 transposed, one launch
__global__ void transpose_cast4(const float* __restrict__ w0, const float* __restrict__ w1,
                                const float* __restrict__ w2, const float* __restrict__ w3,
                                u16* __restrict__ o0, u16* __restrict__ o1,
                                u16* __restrict__ o2, u16* __restrict__ o3) {
  __shared__ float t[32][33];
  const float* W = (blockIdx.z == 0) ? w0 : (blockIdx.z == 1) ? w1 : (blockIdx.z == 2) ? w2 : w3;
  u16* Wt = (blockIdx.z == 0) ? o0 : (blockIdx.z == 1) ? o1 : (blockIdx.z == 2) ? o2 : o3;
  const int tx = threadIdx.x & 31, ty = threadIdx.x >> 5;  // ty 0..7
  const int x0 = blockIdx.x * 32, y0 = blockIdx.y * 32;
#pragma unroll
  for (int i = 0; i < 4; ++i)
    t[ty + i * 8][tx] = W[(size_t)(y0 + ty + i * 8) * HID + x0 + tx];
  __syncthreads();
#pragma unroll
  for (int i = 0; i < 4; ++i)
    Wt[(size_t)(x0 + ty + i * 8) * HID + y0 + tx] = f2bf(t[tx][ty + i * 8]);
}

__global__ void rope_table(float* __restrict__ ctab, float* __restrict__ stab) {
  int idx = blockIdx.x * blockDim.x + threadIdx.x;  // SEQ*64
  int pos = idx >> 6, i = idx & 63;
  float invf = expf(-(float)i * 0.14391156831212787f);  // ln(10000)/64
  float ang = (float)pos * invf;
  float s, c;
  sincosf(ang, &s, &c);
  ctab[idx] = c; stab[idx] = s;
}

// ---------------- QKV GEMM with fused RoPE epilogue (R6, frozen) ----------------

__global__ __launch_bounds__(256, 2) void gemm_qkv_kernel(
    const u16* __restrict__ X, const u16* __restrict__ Wqt, const u16* __restrict__ Wkt,
    const u16* __restrict__ Wvt, u16* __restrict__ Qo, u16* __restrict__ Ko, u16* __restrict__ Vo,
    const float* __restrict__ ctab, const float* __restrict__ stab) {
  __shared__ u16 ldsA[2][8192];
  __shared__ u16 ldsB[2][8192];
  // T1 bijective XCD swizzle: 1536 blocks = 8 * 192
  int flat = (blockIdx.z * 32 + blockIdx.y) * 16 + blockIdx.x;
  int nf = (flat & 7) * 192 + (flat >> 3);
  int bx = nf & 15, by = (nf >> 4) & 31, bz = nf >> 9;
  const u16* Bt = (bz == 0) ? Wqt : (bz == 1) ? Wkt : Wvt;
  u16* Cp = (bz == 0) ? Qo : (bz == 1) ? Ko : Vo;
  const int brow = by * 128, bcol = bx * 128;

  const int lane = threadIdx.x & 63;
  const int wv = threadIdx.x >> 6;
  const int g = lane >> 4, c = lane & 15;
  const int K = HID, N = HID;

  const f32x4 zero = {0.f, 0.f, 0.f, 0.f};
  f32x4 acc[2][8];
#pragma unroll
  for (int m = 0; m < 2; ++m)
#pragma unroll
    for (int n = 0; n < 8; ++n) acc[m][n] = zero;

  auto stage = [&](int buf, int kt) {
    const int k0 = kt * 64;
#pragma unroll
    for (int i = 0; i < 4; ++i) {
      unsigned o = ((unsigned)(wv * 4 + i) * 64 + (unsigned)lane) * 16u;
      unsigned r = o >> 7;                 // tile row (128B rows: 64 bf16)
      unsigned cb = swz<7>(o) & 127u;      // swizzled col-bytes within row
      const size_t gcol = (size_t)k0 + (cb >> 1);
      gload_lds16(X + (size_t)(brow + r) * K + gcol, &ldsA[buf][(wv * 4 + i) * 512]);
      gload_lds16(Bt + (size_t)(bcol + r) * K + gcol, &ldsB[buf][(wv * 4 + i) * 512]);
    }
  };

  stage(0, 0);
  __syncthreads();
  int buf = 0;
  const int nt = K / 64;
  for (int kt = 0; kt < nt; ++kt) {
    if (kt + 1 < nt) stage(buf ^ 1, kt + 1);
    __builtin_amdgcn_s_setprio(1);
#pragma unroll
    for (int s = 0; s < 2; ++s) {
      const unsigned kb = (unsigned)(s * 64 + g * 16);
      bf16x8 af[2], bfv[8];
#pragma unroll
      for (int m = 0; m < 2; ++m) {
        unsigned row = wv * 32 + m * 16 + c;
        af[m] = *(const bf16x8*)((const char*)&ldsA[buf][0] + swz<7>(row * 128 + kb));
      }
#pragma unroll
      for (int n = 0; n < 8; ++n) {
        unsigned row = n * 16 + c;
        bfv[n] = *(const bf16x8*)((const char*)&ldsB[buf][0] + swz<7>(row * 128 + kb));
      }
#pragma unroll
      for (int m = 0; m < 2; ++m)
#pragma unroll
        for (int n = 0; n < 8; ++n)
          acc[m][n] = __builtin_amdgcn_mfma_f32_16x16x32_bf16(af[m], bfv[n], acc[m][n], 0, 0, 0);
    }
    __builtin_amdgcn_s_setprio(0);
    __syncthreads();
    buf ^= 1;
  }

  // epilogue: bz<2 -> rotary in f32 regs (cols bcol+i / bcol+i+64, i = n*16+c, n<4)
  if (bz < 2) {
#pragma unroll
    for (int m = 0; m < 2; ++m) {
      const int rbase = brow + wv * 32 + m * 16 + g * 4;
#pragma unroll
      for (int r = 0; r < 4; ++r) {
        const int pos = rbase + r;
        const float* cp = ctab + (size_t)pos * 64;
        const float* sp = stab + (size_t)pos * 64;
        u16* crow = Cp + (size_t)pos * N + bcol;
#pragma unroll
        for (int n = 0; n < 4; ++n) {
          const int i = n * 16 + c;
          const float x1 = acc[m][n][r], x2 = acc[m][n + 4][r];
          const float co = cp[i], si = sp[i];
          crow[i] = f2bf(x1 * co - x2 * si);
          crow[i + 64] = f2bf(x2 * co + x1 * si);
        }
      }
    }
  } else {
#pragma unroll
    for (int m = 0; m < 2; ++m) {
      const int rbase = brow + wv * 32 + m * 16 + g * 4;
#pragma unroll
      for (int r = 0; r < 4; ++r) {
        u16* crow = Cp + (size_t)(rbase + r) * N + bcol;
#pragma unroll
        for (int n = 0; n < 8; ++n)
          crow[n * 16 + c] = f2bf(acc[m][n][r]);
      }
    }
  }
}

// ---------------- out-proj GEMM (R6, frozen) ----------------

__global__ __launch_bounds__(256, 2) void gemm_out_kernel(
    const u16* __restrict__ Ob, const u16* __restrict__ Wot, float* __restrict__ out) {
  __shared__ u16 ldsA[2][8192];
  __shared__ u16 ldsB[2][8192];
  // 512 blocks = 8 * 64
  int flat = blockIdx.y * 16 + blockIdx.x;
  int nf = (flat & 7) * 64 + (flat >> 3);
  int bx = nf & 15, by = nf >> 4;
  const int brow = by * 128, bcol = bx * 128;

  const int lane = threadIdx.x & 63;
  const int wv = threadIdx.x >> 6;
  const int wr = wv >> 1, wc = wv & 1;
  const int g = lane >> 4, c = lane & 15;
  const int K = HID, N = HID;

  const f32x4 zero = {0.f, 0.f, 0.f, 0.f};
  f32x4 acc[4][4];
#pragma unroll
  for (int m = 0; m < 4; ++m)
#pragma unroll
    for (int n = 0; n < 4; ++n) acc[m][n] = zero;

  auto stage = [&](int buf, int kt) {
    const int k0 = kt * 64;
#pragma unroll
    for (int i = 0; i < 4; ++i) {
      unsigned o = ((unsigned)(wv * 4 + i) * 64 + (unsigned)lane) * 16u;
      unsigned r = o >> 7;
      unsigned cb = swz<7>(o) & 127u;
      const size_t gcol = (size_t)k0 + (cb >> 1);
      gload_lds16(Ob + (size_t)(brow + r) * K + gcol, &ldsA[buf][(wv * 4 + i) * 512]);
      gload_lds16(Wot + (size_t)(bcol + r) * K + gcol, &ldsB[buf][(wv * 4 + i) * 512]);
    }
  };

  stage(0, 0);
  __syncthreads();
  int buf = 0;
  const int nt = K / 64;
  for (int kt = 0; kt < nt; ++kt) {
    if (kt + 1 < nt) stage(buf ^ 1, kt + 1);
    __builtin_amdgcn_s_setprio(1);
#pragma unroll
    for (int s = 0; s < 2; ++s) {
      const unsigned kb = (unsigned)(s * 64 + g * 16);
      bf16x8 af[4], bfv[4];
#pragma unroll
      for (int m = 0; m < 4; ++m) {
        unsigned row = wr * 64 + m * 16 + c;
        af[m] = *(const bf16x8*)((const char*)&ldsA[buf][0] + swz<7>(row * 128 + kb));
      }
#pragma unroll
      for (int n = 0; n < 4; ++n) {
        unsigned row = wc * 64 + n * 16 + c;
        bfv[n] = *(const bf16x8*)((const char*)&ldsB[buf][0] + swz<7>(row * 128 + kb));
      }
#pragma unroll
      for (int m = 0; m < 4; ++m)
#pragma unroll
        for (int n = 0; n < 4; ++n)
          acc[m][n] = __builtin_amdgcn_mfma_f32_16x16x32_bf16(af[m], bfv[n], acc[m][n], 0, 0, 0);
    }
    __builtin_amdgcn_s_setprio(0);
    __syncthreads();
    buf ^= 1;
  }

#pragma unroll
  for (int m = 0; m < 4; ++m) {
    const int rbase = brow + wr * 64 + m * 16 + g * 4;
#pragma unroll
    for (int n = 0; n < 4; ++n) {
      const int cbase = bcol + wc * 64 + n * 16 + c;
#pragma unroll
      for (int r = 0; r < 4; ++r)
        out[(size_t)(rbase + r) * N + cbase] = acc[m][n][r];
    }
  }
}

// ---------------- windowed flash attention: swapped QK^T, in-register softmax (R7, frozen) ----------------

__global__ __launch_bounds__(256, 3) void attn_kernel(
    const u16* __restrict__ Q, const u16* __restrict__ K,
    const u16* __restrict__ V, u16* __restrict__ O) {
  __shared__ u16 k_lds[2][8192];   // [64 keys(pi-rows)][128 d] swz<8> (256B rows), dbuf 32KB
  __shared__ u16 vt_lds[8192];     // V^T [128 d][64 keys] xor-swizzled, single      16KB

  const int lane = threadIdx.x & 63;
  const int wv = threadIdx.x >> 6;
  const int g = lane >> 4;   // 0..3
  const int c = lane & 15;

  // T1: chunked swizzle so one XCD sees contiguous q-blocks of the same head
  int flat = blockIdx.y * 64 + blockIdx.x;       // 1024 = 8 * 128
  int nf = (flat & 7) * 128 + (flat >> 3);
  const int q0 = (nf & 63) * 64;
  const int h = nf >> 6;
  const int qw = q0 + wv * 16;
  const int qpos = qw + c;       // this lane's q row

  // ---- stage Q via k_lds[0] (linear rows), read qf (B-operand layout) ----
#pragma unroll
  for (int i = 0; i < 4; ++i) {
    unsigned o = ((unsigned)(wv * 4 + i) * 64 + (unsigned)lane) * 16u;
    unsigned r = o >> 8;
    unsigned cb = swz<8>(o) & 255u;
    gload_lds16(Q + (size_t)(q0 + r) * HID + h * HD + (cb >> 1), &k_lds[0][(wv * 4 + i) * 512]);
  }
  __syncthreads();
  bf16x8 qf[4];
#pragma unroll
  for (int s = 0; s < 4; ++s) {
    unsigned row = wv * 16 + c;
    qf[s] = *(const bf16x8*)((const char*)&k_lds[0][0] + swz<8>(row * 256 + s * 64 + g * 16));
  }
  __syncthreads();

  auto stageK = [&](int buf, int t0) {
#pragma unroll
    for (int i = 0; i < 4; ++i) {
      unsigned o = ((unsigned)(wv * 4 + i) * 64 + (unsigned)lane) * 16u;
      unsigned r = o >> 8;  // LDS row 0..63
      // pi-inverse: key bits [r5, r3, r2, r4, r1, r0]
      unsigned key = (r & 0x23u) | ((r & 0x0Cu) << 1) | ((r & 0x10u) >> 2);
      unsigned cb = swz<8>(o) & 255u;
      gload_lds16(K + (size_t)(t0 + (int)key) * HID + h * HD + (cb >> 1),
                  &k_lds[buf][(wv * 4 + i) * 512]);
    }
  };
  u16x8 vr[4];
  auto loadV = [&](int t0) {
    const u16x8* src = (const u16x8*)(V + (size_t)(t0 + lane) * HID + h * HD + wv * 32);
#pragma unroll
    for (int it = 0; it < 4; ++it) vr[it] = src[it];
  };
  auto writeVT = [&]() {
#pragma unroll
    for (int it = 0; it < 4; ++it)
#pragma unroll
      for (int j = 0; j < 8; ++j) {
        const int d = wv * 32 + it * 8 + j;
        vt_lds[d * 64 + (lane ^ ((d & 7) << 3))] = vr[it][j];
      }
  };

  const int t_start = (q0 >= WIN) ? (q0 - WIN) : 0;

  // ---- prologue: tile t_start ----
  loadV(t_start);
  stageK(0, t_start);
  __syncthreads();           // drains vm (K + V loads) + rendezvous
  writeVT();
  __syncthreads();           // VT visible

  const f32x4 zero = {0.f, 0.f, 0.f, 0.f};
  float mrow = -1e30f, lrow = 0.f;
  f32x4 oacc[8];
#pragma unroll
  for (int d = 0; d < 8; ++d) oacc[d] = zero;

  const float scale2 = 0.12751743f;  // (1/sqrt(128)) * log2(e)
  int b = 0;

  for (int t0 = t_start; t0 <= q0; t0 += 64) {
    const bool has_next = (t0 + 64 <= q0);
    if (has_next) {
      loadV(t0 + 64);        // issue V first (oldest; vmcnt(4) below waits only these)
      stageK(b ^ 1, t0 + 64);
    }

    // S^T = K Q (swapped): sa[kf] rows = key-slot g*4+r, col = q = c
    f32x4 sa[4];
#pragma unroll
    for (int kf = 0; kf < 4; ++kf) sa[kf] = zero;
    __builtin_amdgcn_s_setprio(1);
#pragma unroll
    for (int s = 0; s < 4; ++s) {
#pragma unroll
      for (int kf = 0; kf < 4; ++kf) {
        unsigned row = kf * 16 + c;
        bf16x8 kb = *(const bf16x8*)((const char*)&k_lds[b][0] + swz<8>(row * 256 + s * 64 + g * 16));
        sa[kf] = __builtin_amdgcn_mfma_f32_16x16x32_bf16(kb, qf[s], sa[kf], 0, 0, 0);
      }
    }
    __builtin_amdgcn_s_setprio(0);

    // semantic key of sa[kf][r]: t0 + (kf>>1)*32 + g*8 + (kf&1)*4 + r
    const bool diag = (t0 == q0);
    const bool lowm = (q0 >= WIN) && (t0 == t_start);
    if (diag) {
#pragma unroll
      for (int kf = 0; kf < 4; ++kf) {
        const int kbase = t0 + (kf >> 1) * 32 + g * 8 + (kf & 1) * 4;
#pragma unroll
        for (int r = 0; r < 4; ++r) {
          float x = sa[kf][r] * scale2;
          sa[kf][r] = (kbase + r <= qpos) ? x : -1e30f;
        }
      }
    } else if (lowm) {
#pragma unroll
      for (int kf = 0; kf < 4; ++kf) {
        const int kbase = t0 + (kf >> 1) * 32 + g * 8 + (kf & 1) * 4;
#pragma unroll
        for (int r = 0; r < 4; ++r) {
          float x = sa[kf][r] * scale2;
          sa[kf][r] = (kbase + r > qpos - WIN) ? x : -1e30f;
        }
      }
    } else {
#pragma unroll
      for (int kf = 0; kf < 4; ++kf)
#pragma unroll
        for (int r = 0; r < 4; ++r) sa[kf][r] *= scale2;
    }

    // row max: in-lane 16 + cross-g
    float tmax = -3e38f;
#pragma unroll
    for (int kf = 0; kf < 4; ++kf)
#pragma unroll
      for (int r = 0; r < 4; ++r) tmax = fmaxf(tmax, sa[kf][r]);
    tmax = fmaxf(tmax, __shfl_xor(tmax, 16));
    tmax = fmaxf(tmax, __shfl_xor(tmax, 32));

    // T13 defer-rescale
    if (!__all((int)(tmax <= mrow + 8.f))) {
      const float mn = fmaxf(mrow, tmax);
      const float al = exp2a(mrow - mn);
      mrow = mn;
      lrow *= al;
      float alo[4];
#pragma unroll
      for (int r = 0; r < 4; ++r) alo[r] = __shfl(al, (lane & 48) | (g * 4 + r));
#pragma unroll
      for (int df = 0; df < 8; ++df)
#pragma unroll
        for (int r = 0; r < 4; ++r) oacc[df][r] *= alo[r];
    }

    // P = exp2(S - m); row-sum
    float rs = 0.f;
    if (diag || lowm) {
#pragma unroll
      for (int kf = 0; kf < 4; ++kf)
#pragma unroll
        for (int r = 0; r < 4; ++r) {
          const float x = sa[kf][r];
          const float p = (x < -1e29f) ? 0.f : exp2a(x - mrow);
          sa[kf][r] = p; rs += p;
        }
    } else {
#pragma unroll
      for (int kf = 0; kf < 4; ++kf)
#pragma unroll
        for (int r = 0; r < 4; ++r) {
          const float p = exp2a(sa[kf][r] - mrow);
          sa[kf][r] = p; rs += p;
        }
    }
    rs += __shfl_xor(rs, 16);
    rs += __shfl_xor(rs, 32);
    lrow += rs;

    // pa from OWN registers (pi-permutation makes P lane-local in A-layout)
    union { bf16x8 v; unsigned u[4]; } pa0, pa1;
    pa0.u[0] = pk2(sa[0][0], sa[0][1]); pa0.u[1] = pk2(sa[0][2], sa[0][3]);
    pa0.u[2] = pk2(sa[1][0], sa[1][1]); pa0.u[3] = pk2(sa[1][2], sa[1][3]);
    pa1.u[0] = pk2(sa[2][0], sa[2][1]); pa1.u[1] = pk2(sa[2][2], sa[2][3]);
    pa1.u[2] = pk2(sa[3][0], sa[3][1]); pa1.u[3] = pk2(sa[3][2], sa[3][3]);

    // O += P V
    __builtin_amdgcn_s_setprio(1);
#pragma unroll
    for (int s2 = 0; s2 < 2; ++s2) {
      const bf16x8 pa = s2 ? pa1.v : pa0.v;
#pragma unroll
      for (int df = 0; df < 8; ++df) {
        const int row = df * 16 + c;
        const bf16x8 vb = *(const bf16x8*)&vt_lds[row * 64 + ((s2 * 32 + g * 8) ^ ((row & 7) << 3))];
        oacc[df] = __builtin_amdgcn_mfma_f32_16x16x32_bf16(pa, vb, oacc[df], 0, 0, 0);
      }
    }
    __builtin_amdgcn_s_setprio(0);

    // barrier1: all waves' K/VT reads retired -> safe to overwrite VT
    asm volatile("s_waitcnt lgkmcnt(0)" ::: "memory");
    __builtin_amdgcn_s_barrier();

    if (has_next) {
      asm volatile("s_waitcnt vmcnt(4)" ::: "memory");  // V regs landed (K gloads may fly)
      writeVT();
    }
    // barrier2: VT writes visible; K(t+1) landed (issued a full tile ago)
    asm volatile("s_waitcnt vmcnt(0) lgkmcnt(0)" ::: "memory");
    __builtin_amdgcn_s_barrier();
    b ^= 1;
  }

  // output: oacc[df][r] = O[qw + g*4 + r][df*16 + c]; l for that row fetched cross-lane
  float ilo[4];
  const float invl = 1.f / lrow;
#pragma unroll
  for (int r = 0; r < 4; ++r) ilo[r] = __shfl(invl, (lane & 48) | (g * 4 + r));
#pragma unroll
  for (int df = 0; df < 8; ++df)
#pragma unroll
    for (int r = 0; r < 4; ++r) {
      const int row = qw + g * 4 + r;
      const int col = h * HD + df * 16 + c;
      O[(size_t)row * HID + col] = f2bf(oacc[df][r] * ilo[r]);
    }
}

// ---------------- launch ----------------

extern "C" void kernel_launch(void* const* d_in, const int* in_sizes, int n_in,
                              void* d_out, int out_size, void* d_ws, size_t ws_size,
                              hipStream_t stream) {
  const float* hidden = (const float*)d_in[0];
  const float* wq = (const float*)d_in[1];
  const float* wk = (const float*)d_in[2];
  const float* wv = (const float*)d_in[3];
  const float* wo = (const float*)d_in[4];
  float* out = (float*)d_out;

  char* ws = (char*)d_ws;
  u16* Xb  = (u16*)ws;                 ws += (size_t)SEQ * HID * 2;
  u16* Wqt = (u16*)ws;                 ws += (size_t)HID * HID * 2;
  u16* Wkt = (u16*)ws;                 ws += (size_t)HID * HID * 2;
  u16* Wvt = (u16*)ws;                 ws += (size_t)HID * HID * 2;
  u16* Wot = (u16*)ws;                 ws += (size_t)HID * HID * 2;
  u16* Qb  = (u16*)ws;                 ws += (size_t)SEQ * HID * 2;
  u16* Kb  = (u16*)ws;                 ws += (size_t)SEQ * HID * 2;
  u16* Vb  = (u16*)ws;                 ws += (size_t)SEQ * HID * 2;
  u16* Ob  = (u16*)ws;                 ws += (size_t)SEQ * HID * 2;
  float* ctab = (float*)ws;            ws += (size_t)SEQ * 64 * 4;
  float* stab = (float*)ws;            ws += (size_t)SEQ * 64 * 4;

  cast_f32_bf16<<<(SEQ * HID / 4 + 255) / 256, 256, 0, stream>>>(hidden, Xb, SEQ * HID / 4);

  dim3 tg(64, 64, 4);
  transpose_cast4<<<tg, 256, 0, stream>>>(wq, wk, wv, wo, Wqt, Wkt, Wvt, Wot);

  rope_table<<<(SEQ * 64) / 256, 256, 0, stream>>>(ctab, stab);

  dim3 gq(HID / 128, SEQ / 128, 3);
  gemm_qkv_kernel<<<gq, 256, 0, stream>>>(Xb, Wqt, Wkt, Wvt, Qb, Kb, Vb, ctab, stab);

  dim3 ga(SEQ / 64, NH);
  attn_kernel<<<ga, 256, 0, stream>>>(Qb, Kb, Vb, Ob);

  dim3 go(HID / 128, SEQ / 128);
  gemm_out_kernel<<<go, 256, 0, stream>>>(Ob, Wot, out);
}

// Round 10
// 260.541 us; speedup vs baseline: 1.3840x; 1.0161x over previous
//
#include <hip/hip_runtime.h>
#include <cstdint>
#include <cstddef>

typedef unsigned short u16;
typedef __bf16 bf16x8 __attribute__((ext_vector_type(8)));
typedef float f32x4 __attribute__((ext_vector_type(4)));
typedef unsigned short u16x8 __attribute__((ext_vector_type(8)));

#define SEQ 4096
#define HID 2048
#define NH 16
#define HD 128
#define WIN 1024

__device__ __forceinline__ float bf2f(u16 u) {
  union { unsigned int i; float f; } v; v.i = ((unsigned int)u) << 16; return v.f;
}
__device__ __forceinline__ u16 f2bf(float f) {
  union { float f; unsigned int i; } v; v.f = f;
  unsigned int r = v.i + 0x7FFFu + ((v.i >> 16) & 1u);
  return (u16)(r >> 16);
}
__device__ __forceinline__ u16 f2bf_rne(float f) {
  union { __bf16 b; u16 u; } v; v.b = (__bf16)f; return v.u;
}
__device__ __forceinline__ unsigned pk2(float lo, float hi) {
  return (unsigned)f2bf_rne(lo) | ((unsigned)f2bf_rne(hi) << 16);
}
__device__ __forceinline__ float exp2a(float x) {
  float r; asm("v_exp_f32 %0, %1" : "=v"(r) : "v"(x)); return r;
}
// XOR swizzle within a tile whose rows are (1<<L2R) bytes. Involution; keeps 16B alignment.
template<int L2R>
__device__ __forceinline__ unsigned swz(unsigned o) { return o ^ (((o >> L2R) & 7u) << 4); }

__device__ __forceinline__ void gload_lds16(const u16* g, u16* l) {
  __builtin_amdgcn_global_load_lds((const __attribute__((address_space(1))) void*)g,
                                   (__attribute__((address_space(3))) void*)l, 16, 0, 0);
}

// ---------------- fused prep: cast + 4 weight transposes + rope table ----------------
// grid (64,64,6): z=0 cast hidden->bf16; z=1..4 transpose+cast W(z-1); z=5 rope table.

__global__ void prep_kernel(const float* __restrict__ hidden,
                            const float* __restrict__ w0, const float* __restrict__ w1,
                            const float* __restrict__ w2, const float* __restrict__ w3,
                            u16* __restrict__ Xb,
                            u16* __restrict__ o0, u16* __restrict__ o1,
                            u16* __restrict__ o2, u16* __restrict__ o3,
                            float* __restrict__ ctab, float* __restrict__ stab) {
  const int z = blockIdx.z;
  const int blk = blockIdx.y * 64 + blockIdx.x;  // 0..4095
  if (z == 0) {
    // cast: SEQ*HID/4 = 2,097,152 float4; 4096 blocks x 256 thr x 2
    int idx0 = blk * 256 + threadIdx.x;
#pragma unroll
    for (int t = 0; t < 2; ++t) {
      int i = idx0 + t * (4096 * 256);
      float4 v = ((const float4*)hidden)[i];
      union { u16 u[4]; unsigned long long ll; } r;
      r.u[0] = f2bf(v.x); r.u[1] = f2bf(v.y); r.u[2] = f2bf(v.z); r.u[3] = f2bf(v.w);
      ((unsigned long long*)Xb)[i] = r.ll;
    }
  } else if (z <= 4) {
    __shared__ float t[32][33];
    const float* W = (z == 1) ? w0 : (z == 2) ? w1 : (z == 3) ? w2 : w3;
    u16* Wt = (z == 1) ? o0 : (z == 2) ? o1 : (z == 3) ? o2 : o3;
    const int tx = threadIdx.x & 31, ty = threadIdx.x >> 5;  // ty 0..7
    const int x0 = blockIdx.x * 32, y0 = blockIdx.y * 32;
#pragma unroll
    for (int i = 0; i < 4; ++i)
      t[ty + i * 8][tx] = W[(size_t)(y0 + ty + i * 8) * HID + x0 + tx];
    __syncthreads();
#pragma unroll
    for (int i = 0; i < 4; ++i)
      Wt[(size_t)(x0 + ty + i * 8) * HID + y0 + tx] = f2bf(t[tx][ty + i * 8]);
  } else {
    // rope table: SEQ*64 = 262144 entries; first 1024 blocks
    if (blk < 1024) {
      int idx = blk * 256 + threadIdx.x;
      int pos = idx >> 6, i = idx & 63;
      float invf = expf(-(float)i * 0.14391156831212787f);  // ln(10000)/64
      float ang = (float)pos * invf;
      float s, c;
      sincosf(ang, &s, &c);
      ctab[idx] = c; stab[idx] = s;
    }
  }
}

// ---------------- QKV GEMM, fused RoPE: 8-wave 128x128 2-phase ----------------
// Same proven sync skeleton as R6 (dbuf LDS, depth-1 global_load_lds stage, swz<7>,
// __syncthreads, setprio). Parameter change only: 512 threads (8 waves) -> 16 waves/CU
// at 2 blocks/CU (4/SIMD TLP vs 2) to hide the barrier vmcnt-drain + ds latency.
// Wave (wr=wv>>2, wc=wv&3): rows wr*64+[0,64), col-frags {wc, wc+4} -> each thread
// holds cols i and i+64 (RoPE pairs in-register, R8-verified nmap pattern).

__global__ __launch_bounds__(512, 4) void gemm_qkv_kernel(
    const u16* __restrict__ X, const u16* __restrict__ Wqt, const u16* __restrict__ Wkt,
    const u16* __restrict__ Wvt, u16* __restrict__ Qo, u16* __restrict__ Ko, u16* __restrict__ Vo,
    const float* __restrict__ ctab, const float* __restrict__ stab) {
  __shared__ u16 ldsA[2][8192];
  __shared__ u16 ldsB[2][8192];
  // T1 bijective XCD swizzle: 1536 blocks = 8 * 192
  int flat = (blockIdx.z * 32 + blockIdx.y) * 16 + blockIdx.x;
  int nf = (flat & 7) * 192 + (flat >> 3);
  int bx = nf & 15, by = (nf >> 4) & 31, bz = nf >> 9;
  const u16* Bt = (bz == 0) ? Wqt : (bz == 1) ? Wkt : Wvt;
  u16* Cp = (bz == 0) ? Qo : (bz == 1) ? Ko : Vo;
  const int brow = by * 128, bcol = bx * 128;

  const int tid = threadIdx.x;
  const int lane = tid & 63;
  const int wv = tid >> 6;       // 0..7
  const int wr = wv >> 2;        // 0..1 : rows wr*64 + [0,64)
  const int wc = wv & 3;         // 0..3 : col-frags {wc, wc+4}
  const int g = lane >> 4, c = lane & 15;
  const int K = HID, N = HID;

  const f32x4 zero = {0.f, 0.f, 0.f, 0.f};
  f32x4 acc[4][2];
#pragma unroll
  for (int m = 0; m < 4; ++m)
#pragma unroll
    for (int j = 0; j < 2; ++j) acc[m][j] = zero;

  auto stage = [&](int buf, int kt) {
    const int k0 = kt * 64;
#pragma unroll
    for (int i = 0; i < 2; ++i) {
      unsigned idx = (unsigned)(wv * 128 + i * 64 + lane);  // 0..1023
      unsigned o = idx * 16u;
      unsigned r = o >> 7;                 // tile row (128B rows: 64 bf16)
      unsigned cb = swz<7>(o) & 127u;      // swizzled col-bytes within row
      const size_t gcol = (size_t)k0 + (cb >> 1);
      gload_lds16(X + (size_t)(brow + r) * K + gcol, &ldsA[buf][idx * 8]);
      gload_lds16(Bt + (size_t)(bcol + r) * K + gcol, &ldsB[buf][idx * 8]);
    }
  };

  stage(0, 0);
  __syncthreads();
  int buf = 0;
  const int nt = K / 64;
  for (int kt = 0; kt < nt; ++kt) {
    if (kt + 1 < nt) stage(buf ^ 1, kt + 1);
    __builtin_amdgcn_s_setprio(1);
#pragma unroll
    for (int s = 0; s < 2; ++s) {
      const unsigned kb = (unsigned)(s * 64 + g * 16);
      bf16x8 af[4], bfv[2];
#pragma unroll
      for (int m = 0; m < 4; ++m) {
        unsigned row = (unsigned)(wr * 64 + m * 16 + c);
        af[m] = *(const bf16x8*)((const char*)&ldsA[buf][0] + swz<7>(row * 128 + kb));
      }
#pragma unroll
      for (int j = 0; j < 2; ++j) {
        unsigned row = (unsigned)((wc + j * 4) * 16 + c);
        bfv[j] = *(const bf16x8*)((const char*)&ldsB[buf][0] + swz<7>(row * 128 + kb));
      }
#pragma unroll
      for (int m = 0; m < 4; ++m)
#pragma unroll
        for (int j = 0; j < 2; ++j)
          acc[m][j] = __builtin_amdgcn_mfma_f32_16x16x32_bf16(af[m], bfv[j], acc[m][j], 0, 0, 0);
    }
    __builtin_amdgcn_s_setprio(0);
    __syncthreads();
    buf ^= 1;
  }

  // epilogue: acc[m][j] -> row = brow + wr*64 + m*16 + g*4 + r,
  //           col = bcol + (wc + j*4)*16 + c ; j=0/1 are 64 cols apart (rotary pair).
  if (bz < 2) {
#pragma unroll
    for (int m = 0; m < 4; ++m) {
      const int rbase = brow + wr * 64 + m * 16 + g * 4;
#pragma unroll
      for (int r = 0; r < 4; ++r) {
        const int pos = rbase + r;
        const int i = wc * 16 + c;
        const float co = ctab[(size_t)pos * 64 + i];
        const float si = stab[(size_t)pos * 64 + i];
        u16* crow = Cp + (size_t)pos * N + bcol;
        const float x1 = acc[m][0][r], x2 = acc[m][1][r];
        crow[i] = f2bf(x1 * co - x2 * si);
        crow[i + 64] = f2bf(x2 * co + x1 * si);
      }
    }
  } else {
#pragma unroll
    for (int m = 0; m < 4; ++m) {
      const int rbase = brow + wr * 64 + m * 16 + g * 4;
#pragma unroll
      for (int r = 0; r < 4; ++r) {
        u16* crow = Cp + (size_t)(rbase + r) * N + bcol;
        crow[wc * 16 + c] = f2bf(acc[m][0][r]);
        crow[wc * 16 + 64 + c] = f2bf(acc[m][1][r]);
      }
    }
  }
}

// ---------------- out-proj GEMM (R6, frozen) ----------------

__global__ __launch_bounds__(256, 2) void gemm_out_kernel(
    const u16* __restrict__ Ob, const u16* __restrict__ Wot, float* __restrict__ out) {
  __shared__ u16 ldsA[2][8192];
  __shared__ u16 ldsB[2][8192];
  // 512 blocks = 8 * 64
  int flat = blockIdx.y * 16 + blockIdx.x;
  int nf = (flat & 7) * 64 + (flat >> 3);
  int bx = nf & 15, by = nf >> 4;
  const int brow = by * 128, bcol = bx * 128;

  const int lane = threadIdx.x & 63;
  const int wv = threadIdx.x >> 6;
  const int wr = wv >> 1, wc = wv & 1;
  const int g = lane >> 4, c = lane & 15;
  const int K = HID, N = HID;

  const f32x4 zero = {0.f, 0.f, 0.f, 0.f};
  f32x4 acc[4][4];
#pragma unroll
  for (int m = 0; m < 4; ++m)
#pragma unroll
    for (int n = 0; n < 4; ++n) acc[m][n] = zero;

  auto stage = [&](int buf, int kt) {
    const int k0 = kt * 64;
#pragma unroll
    for (int i = 0; i < 4; ++i) {
      unsigned o = ((unsigned)(wv * 4 + i) * 64 + (unsigned)lane) * 16u;
      unsigned r = o >> 7;
      unsigned cb = swz<7>(o) & 127u;
      const size_t gcol = (size_t)k0 + (cb >> 1);
      gload_lds16(Ob + (size_t)(brow + r) * K + gcol, &ldsA[buf][(wv * 4 + i) * 512]);
      gload_lds16(Wot + (size_t)(bcol + r) * K + gcol, &ldsB[buf][(wv * 4 + i) * 512]);
    }
  };

  stage(0, 0);
  __syncthreads();
  int buf = 0;
  const int nt = K / 64;
  for (int kt = 0; kt < nt; ++kt) {
    if (kt + 1 < nt) stage(buf ^ 1, kt + 1);
    __builtin_amdgcn_s_setprio(1);
#pragma unroll
    for (int s = 0; s < 2; ++s) {
      const unsigned kb = (unsigned)(s * 64 + g * 16);
      bf16x8 af[4], bfv[4];
#pragma unroll
      for (int m = 0; m < 4; ++m) {
        unsigned row = wr * 64 + m * 16 + c;
        af[m] = *(const bf16x8*)((const char*)&ldsA[buf][0] + swz<7>(row * 128 + kb));
      }
#pragma unroll
      for (int n = 0; n < 4; ++n) {
        unsigned row = wc * 64 + n * 16 + c;
        bfv[n] = *(const bf16x8*)((const char*)&ldsB[buf][0] + swz<7>(row * 128 + kb));
      }
#pragma unroll
      for (int m = 0; m < 4; ++m)
#pragma unroll
        for (int n = 0; n < 4; ++n)
          acc[m][n] = __builtin_amdgcn_mfma_f32_16x16x32_bf16(af[m], bfv[n], acc[m][n], 0, 0, 0);
    }
    __builtin_amdgcn_s_setprio(0);
    __syncthreads();
    buf ^= 1;
  }

#pragma unroll
  for (int m = 0; m < 4; ++m) {
    const int rbase = brow + wr * 64 + m * 16 + g * 4;
#pragma unroll
    for (int n = 0; n < 4; ++n) {
      const int cbase = bcol + wc * 64 + n * 16 + c;
#pragma unroll
      for (int r = 0; r < 4; ++r)
        out[(size_t)(rbase + r) * N + cbase] = acc[m][n][r];
    }
  }
}

// ---------------- windowed flash attention: swapped QK^T, in-register softmax (R7, frozen) ----------------

__global__ __launch_bounds__(256, 3) void attn_kernel(
    const u16* __restrict__ Q, const u16* __restrict__ K,
    const u16* __restrict__ V, u16* __restrict__ O) {
  __shared__ u16 k_lds[2][8192];   // [64 keys(pi-rows)][128 d] swz<8> (256B rows), dbuf 32KB
  __shared__ u16 vt_lds[8192];     // V^T [128 d][64 keys] xor-swizzled, single      16KB

  const int lane = threadIdx.x & 63;
  const int wv = threadIdx.x >> 6;
  const int g = lane >> 4;   // 0..3
  const int c = lane & 15;

  // T1: chunked swizzle so one XCD sees contiguous q-blocks of the same head
  int flat = blockIdx.y * 64 + blockIdx.x;       // 1024 = 8 * 128
  int nf = (flat & 7) * 128 + (flat >> 3);
  const int q0 = (nf & 63) * 64;
  const int h = nf >> 6;
  const int qw = q0 + wv * 16;
  const int qpos = qw + c;       // this lane's q row

  // ---- stage Q via k_lds[0] (linear rows), read qf (B-operand layout) ----
#pragma unroll
  for (int i = 0; i < 4; ++i) {
    unsigned o = ((unsigned)(wv * 4 + i) * 64 + (unsigned)lane) * 16u;
    unsigned r = o >> 8;
    unsigned cb = swz<8>(o) & 255u;
    gload_lds16(Q + (size_t)(q0 + r) * HID + h * HD + (cb >> 1), &k_lds[0][(wv * 4 + i) * 512]);
  }
  __syncthreads();
  bf16x8 qf[4];
#pragma unroll
  for (int s = 0; s < 4; ++s) {
    unsigned row = wv * 16 + c;
    qf[s] = *(const bf16x8*)((const char*)&k_lds[0][0] + swz<8>(row * 256 + s * 64 + g * 16));
  }
  __syncthreads();

  auto stageK = [&](int buf, int t0) {
#pragma unroll
    for (int i = 0; i < 4; ++i) {
      unsigned o = ((unsigned)(wv * 4 + i) * 64 + (unsigned)lane) * 16u;
      unsigned r = o >> 8;  // LDS row 0..63
      // pi-inverse: key bits [r5, r3, r2, r4, r1, r0]
      unsigned key = (r & 0x23u) | ((r & 0x0Cu) << 1) | ((r & 0x10u) >> 2);
      unsigned cb = swz<8>(o) & 255u;
      gload_lds16(K + (size_t)(t0 + (int)key) * HID + h * HD + (cb >> 1),
                  &k_lds[buf][(wv * 4 + i) * 512]);
    }
  };
  u16x8 vr[4];
  auto loadV = [&](int t0) {
    const u16x8* src = (const u16x8*)(V + (size_t)(t0 + lane) * HID + h * HD + wv * 32);
#pragma unroll
    for (int it = 0; it < 4; ++it) vr[it] = src[it];
  };
  auto writeVT = [&]() {
#pragma unroll
    for (int it = 0; it < 4; ++it)
#pragma unroll
      for (int j = 0; j < 8; ++j) {
        const int d = wv * 32 + it * 8 + j;
        vt_lds[d * 64 + (lane ^ ((d & 7) << 3))] = vr[it][j];
      }
  };

  const int t_start = (q0 >= WIN) ? (q0 - WIN) : 0;

  // ---- prologue: tile t_start ----
  loadV(t_start);
  stageK(0, t_start);
  __syncthreads();           // drains vm (K + V loads) + rendezvous
  writeVT();
  __syncthreads();           // VT visible

  const f32x4 zero = {0.f, 0.f, 0.f, 0.f};
  float mrow = -1e30f, lrow = 0.f;
  f32x4 oacc[8];
#pragma unroll
  for (int d = 0; d < 8; ++d) oacc[d] = zero;

  const float scale2 = 0.12751743f;  // (1/sqrt(128)) * log2(e)
  int b = 0;

  for (int t0 = t_start; t0 <= q0; t0 += 64) {
    const bool has_next = (t0 + 64 <= q0);
    if (has_next) {
      loadV(t0 + 64);        // issue V first (oldest; vmcnt(4) below waits only these)
      stageK(b ^ 1, t0 + 64);
    }

    // S^T = K Q (swapped): sa[kf] rows = key-slot g*4+r, col = q = c
    f32x4 sa[4];
#pragma unroll
    for (int kf = 0; kf < 4; ++kf) sa[kf] = zero;
    __builtin_amdgcn_s_setprio(1);
#pragma unroll
    for (int s = 0; s < 4; ++s) {
#pragma unroll
      for (int kf = 0; kf < 4; ++kf) {
        unsigned row = kf * 16 + c;
        bf16x8 kb = *(const bf16x8*)((const char*)&k_lds[b][0] + swz<8>(row * 256 + s * 64 + g * 16));
        sa[kf] = __builtin_amdgcn_mfma_f32_16x16x32_bf16(kb, qf[s], sa[kf], 0, 0, 0);
      }
    }
    __builtin_amdgcn_s_setprio(0);

    // semantic key of sa[kf][r]: t0 + (kf>>1)*32 + g*8 + (kf&1)*4 + r
    const bool diag = (t0 == q0);
    const bool lowm = (q0 >= WIN) && (t0 == t_start);
    if (diag) {
#pragma unroll
      for (int kf = 0; kf < 4; ++kf) {
        const int kbase = t0 + (kf >> 1) * 32 + g * 8 + (kf & 1) * 4;
#pragma unroll
        for (int r = 0; r < 4; ++r) {
          float x = sa[kf][r] * scale2;
          sa[kf][r] = (kbase + r <= qpos) ? x : -1e30f;
        }
      }
    } else if (lowm) {
#pragma unroll
      for (int kf = 0; kf < 4; ++kf) {
        const int kbase = t0 + (kf >> 1) * 32 + g * 8 + (kf & 1) * 4;
#pragma unroll
        for (int r = 0; r < 4; ++r) {
          float x = sa[kf][r] * scale2;
          sa[kf][r] = (kbase + r > qpos - WIN) ? x : -1e30f;
        }
      }
    } else {
#pragma unroll
      for (int kf = 0; kf < 4; ++kf)
#pragma unroll
        for (int r = 0; r < 4; ++r) sa[kf][r] *= scale2;
    }

    // row max: in-lane 16 + cross-g
    float tmax = -3e38f;
#pragma unroll
    for (int kf = 0; kf < 4; ++kf)
#pragma unroll
      for (int r = 0; r < 4; ++r) tmax = fmaxf(tmax, sa[kf][r]);
    tmax = fmaxf(tmax, __shfl_xor(tmax, 16));
    tmax = fmaxf(tmax, __shfl_xor(tmax, 32));

    // T13 defer-rescale
    if (!__all((int)(tmax <= mrow + 8.f))) {
      const float mn = fmaxf(mrow, tmax);
      const float al = exp2a(mrow - mn);
      mrow = mn;
      lrow *= al;
      float alo[4];
#pragma unroll
      for (int r = 0; r < 4; ++r) alo[r] = __shfl(al, (lane & 48) | (g * 4 + r));
#pragma unroll
      for (int df = 0; df < 8; ++df)
#pragma unroll
        for (int r = 0; r < 4; ++r) oacc[df][r] *= alo[r];
    }

    // P = exp2(S - m); row-sum
    float rs = 0.f;
    if (diag || lowm) {
#pragma unroll
      for (int kf = 0; kf < 4; ++kf)
#pragma unroll
        for (int r = 0; r < 4; ++r) {
          const float x = sa[kf][r];
          const float p = (x < -1e29f) ? 0.f : exp2a(x - mrow);
          sa[kf][r] = p; rs += p;
        }
    } else {
#pragma unroll
      for (int kf = 0; kf < 4; ++kf)
#pragma unroll
        for (int r = 0; r < 4; ++r) {
          const float p = exp2a(sa[kf][r] - mrow);
          sa[kf][r] = p; rs += p;
        }
    }
    rs += __shfl_xor(rs, 16);
    rs += __shfl_xor(rs, 32);
    lrow += rs;

    // pa from OWN registers (pi-permutation makes P lane-local in A-layout)
    union { bf16x8 v; unsigned u[4]; } pa0, pa1;
    pa0.u[0] = pk2(sa[0][0], sa[0][1]); pa0.u[1] = pk2(sa[0][2], sa[0][3]);
    pa0.u[2] = pk2(sa[1][0], sa[1][1]); pa0.u[3] = pk2(sa[1][2], sa[1][3]);
    pa1.u[0] = pk2(sa[2][0], sa[2][1]); pa1.u[1] = pk2(sa[2][2], sa[2][3]);
    pa1.u[2] = pk2(sa[3][0], sa[3][1]); pa1.u[3] = pk2(sa[3][2], sa[3][3]);

    // O += P V
    __builtin_amdgcn_s_setprio(1);
#pragma unroll
    for (int s2 = 0; s2 < 2; ++s2) {
      const bf16x8 pa = s2 ? pa1.v : pa0.v;
#pragma unroll
      for (int df = 0; df < 8; ++df) {
        const int row = df * 16 + c;
        const bf16x8 vb = *(const bf16x8*)&vt_lds[row * 64 + ((s2 * 32 + g * 8) ^ ((row & 7) << 3))];
        oacc[df] = __builtin_amdgcn_mfma_f32_16x16x32_bf16(pa, vb, oacc[df], 0, 0, 0);
      }
    }
    __builtin_amdgcn_s_setprio(0);

    // barrier1: all waves' K/VT reads retired -> safe to overwrite VT
    asm volatile("s_waitcnt lgkmcnt(0)" ::: "memory");
    __builtin_amdgcn_s_barrier();

    if (has_next) {
      asm volatile("s_waitcnt vmcnt(4)" ::: "memory");  // V regs landed (K gloads may fly)
      writeVT();
    }
    // barrier2: VT writes visible; K(t+1) landed (issued a full tile ago)
    asm volatile("s_waitcnt vmcnt(0) lgkmcnt(0)" ::: "memory");
    __builtin_amdgcn_s_barrier();
    b ^= 1;
  }

  // output: oacc[df][r] = O[qw + g*4 + r][df*16 + c]; l for that row fetched cross-lane
  float ilo[4];
  const float invl = 1.f / lrow;
#pragma unroll
  for (int r = 0; r < 4; ++r) ilo[r] = __shfl(invl, (lane & 48) | (g * 4 + r));
#pragma unroll
  for (int df = 0; df < 8; ++df)
#pragma unroll
    for (int r = 0; r < 4; ++r) {
      const int row = qw + g * 4 + r;
      const int col = h * HD + df * 16 + c;
      O[(size_t)row * HID + col] = f2bf(oacc[df][r] * ilo[r]);
    }
}

// ---------------- launch ----------------

extern "C" void kernel_launch(void* const* d_in, const int* in_sizes, int n_in,
                              void* d_out, int out_size, void* d_ws, size_t ws_size,
                              hipStream_t stream) {
  const float* hidden = (const float*)d_in[0];
  const float* wq = (const float*)d_in[1];
  const float* wk = (const float*)d_in[2];
  const float* wv = (const float*)d_in[3];
  const float* wo = (const float*)d_in[4];
  float* out = (float*)d_out;

  char* ws = (char*)d_ws;
  u16* Xb  = (u16*)ws;                 ws += (size_t)SEQ * HID * 2;
  u16* Wqt = (u16*)ws;                 ws += (size_t)HID * HID * 2;
  u16* Wkt = (u16*)ws;                 ws += (size_t)HID * HID * 2;
  u16* Wvt = (u16*)ws;                 ws += (size_t)HID * HID * 2;
  u16* Wot = (u16*)ws;                 ws += (size_t)HID * HID * 2;
  u16* Qb  = (u16*)ws;                 ws += (size_t)SEQ * HID * 2;
  u16* Kb  = (u16*)ws;                 ws += (size_t)SEQ * HID * 2;
  u16* Vb  = (u16*)ws;                 ws += (size_t)SEQ * HID * 2;
  u16* Ob  = (u16*)ws;                 ws += (size_t)SEQ * HID * 2;
  float* ctab = (float*)ws;            ws += (size_t)SEQ * 64 * 4;
  float* stab = (float*)ws;            ws += (size_t)SEQ * 64 * 4;

  dim3 gp(64, 64, 6);
  prep_kernel<<<gp, 256, 0, stream>>>(hidden, wq, wk, wv, wo, Xb, Wqt, Wkt, Wvt, Wot, ctab, stab);

  dim3 gq(HID / 128, SEQ / 128, 3);
  gemm_qkv_kernel<<<gq, 512, 0, stream>>>(Xb, Wqt, Wkt, Wvt, Qb, Kb, Vb, ctab, stab);

  dim3 ga(SEQ / 64, NH);
  attn_kernel<<<ga, 256, 0, stream>>>(Qb, Kb, Vb, Ob);

  dim3 go(HID / 128, SEQ / 128);
  gemm_out_kernel<<<go, 256, 0, stream>>>(Ob, Wot, out);
}

// Round 11
// 259.887 us; speedup vs baseline: 1.3875x; 1.0025x over previous
//
#include <hip/hip_runtime.h>
#include <cstdint>
#include <cstddef>

typedef unsigned short u16;
typedef __bf16 bf16x8 __attribute__((ext_vector_type(8)));
typedef float f32x4 __attribute__((ext_vector_type(4)));
typedef unsigned short u16x8 __attribute__((ext_vector_type(8)));

#define SEQ 4096
#define HID 2048
#define NH 16
#define HD 128
#define WIN 1024

__device__ __forceinline__ float bf2f(u16 u) {
  union { unsigned int i; float f; } v; v.i = ((unsigned int)u) << 16; return v.f;
}
__device__ __forceinline__ u16 f2bf(float f) {
  union { float f; unsigned int i; } v; v.f = f;
  unsigned int r = v.i + 0x7FFFu + ((v.i >> 16) & 1u);
  return (u16)(r >> 16);
}
__device__ __forceinline__ u16 f2bf_rne(float f) {
  union { __bf16 b; u16 u; } v; v.b = (__bf16)f; return v.u;
}
__device__ __forceinline__ unsigned pk2(float lo, float hi) {
  return (unsigned)f2bf_rne(lo) | ((unsigned)f2bf_rne(hi) << 16);
}
__device__ __forceinline__ float exp2a(float x) {
  float r; asm("v_exp_f32 %0, %1" : "=v"(r) : "v"(x)); return r;
}
// XOR swizzle within a tile whose rows are (1<<L2R) bytes. Involution; keeps 16B alignment.
template<int L2R>
__device__ __forceinline__ unsigned swz(unsigned o) { return o ^ (((o >> L2R) & 7u) << 4); }

__device__ __forceinline__ void gload_lds16(const u16* g, u16* l) {
  __builtin_amdgcn_global_load_lds((const __attribute__((address_space(1))) void*)g,
                                   (__attribute__((address_space(3))) void*)l, 16, 0, 0);
}

// ---------------- fused prep: cast + 4 weight transposes + rope table ----------------
// grid (64,64,6): z=0 cast hidden->bf16; z=1..4 transpose+cast W(z-1); z=5 rope table.

__global__ void prep_kernel(const float* __restrict__ hidden,
                            const float* __restrict__ w0, const float* __restrict__ w1,
                            const float* __restrict__ w2, const float* __restrict__ w3,
                            u16* __restrict__ Xb,
                            u16* __restrict__ o0, u16* __restrict__ o1,
                            u16* __restrict__ o2, u16* __restrict__ o3,
                            float* __restrict__ ctab, float* __restrict__ stab) {
  const int z = blockIdx.z;
  const int blk = blockIdx.y * 64 + blockIdx.x;  // 0..4095
  if (z == 0) {
    // cast: SEQ*HID/4 = 2,097,152 float4; 4096 blocks x 256 thr x 2
    int idx0 = blk * 256 + threadIdx.x;
#pragma unroll
    for (int t = 0; t < 2; ++t) {
      int i = idx0 + t * (4096 * 256);
      float4 v = ((const float4*)hidden)[i];
      union { u16 u[4]; unsigned long long ll; } r;
      r.u[0] = f2bf(v.x); r.u[1] = f2bf(v.y); r.u[2] = f2bf(v.z); r.u[3] = f2bf(v.w);
      ((unsigned long long*)Xb)[i] = r.ll;
    }
  } else if (z <= 4) {
    __shared__ float t[32][33];
    const float* W = (z == 1) ? w0 : (z == 2) ? w1 : (z == 3) ? w2 : w3;
    u16* Wt = (z == 1) ? o0 : (z == 2) ? o1 : (z == 3) ? o2 : o3;
    const int tx = threadIdx.x & 31, ty = threadIdx.x >> 5;  // ty 0..7
    const int x0 = blockIdx.x * 32, y0 = blockIdx.y * 32;
#pragma unroll
    for (int i = 0; i < 4; ++i)
      t[ty + i * 8][tx] = W[(size_t)(y0 + ty + i * 8) * HID + x0 + tx];
    __syncthreads();
#pragma unroll
    for (int i = 0; i < 4; ++i)
      Wt[(size_t)(x0 + ty + i * 8) * HID + y0 + tx] = f2bf(t[tx][ty + i * 8]);
  } else {
    // rope table: SEQ*64 = 262144 entries; first 1024 blocks
    if (blk < 1024) {
      int idx = blk * 256 + threadIdx.x;
      int pos = idx >> 6, i = idx & 63;
      float invf = expf(-(float)i * 0.14391156831212787f);  // ln(10000)/64
      float ang = (float)pos * invf;
      float s, c;
      sincosf(ang, &s, &c);
      ctab[idx] = c; stab[idx] = s;
    }
  }
}

// ---------------- QKV GEMM, fused RoPE: 8-wave 128x128 2-phase (R10, frozen) ----------------

__global__ __launch_bounds__(512, 4) void gemm_qkv_kernel(
    const u16* __restrict__ X, const u16* __restrict__ Wqt, const u16* __restrict__ Wkt,
    const u16* __restrict__ Wvt, u16* __restrict__ Qo, u16* __restrict__ Ko, u16* __restrict__ Vo,
    const float* __restrict__ ctab, const float* __restrict__ stab) {
  __shared__ u16 ldsA[2][8192];
  __shared__ u16 ldsB[2][8192];
  // T1 bijective XCD swizzle: 1536 blocks = 8 * 192
  int flat = (blockIdx.z * 32 + blockIdx.y) * 16 + blockIdx.x;
  int nf = (flat & 7) * 192 + (flat >> 3);
  int bx = nf & 15, by = (nf >> 4) & 31, bz = nf >> 9;
  const u16* Bt = (bz == 0) ? Wqt : (bz == 1) ? Wkt : Wvt;
  u16* Cp = (bz == 0) ? Qo : (bz == 1) ? Ko : Vo;
  const int brow = by * 128, bcol = bx * 128;

  const int tid = threadIdx.x;
  const int lane = tid & 63;
  const int wv = tid >> 6;       // 0..7
  const int wr = wv >> 2;        // 0..1 : rows wr*64 + [0,64)
  const int wc = wv & 3;         // 0..3 : col-frags {wc, wc+4}
  const int g = lane >> 4, c = lane & 15;
  const int K = HID, N = HID;

  const f32x4 zero = {0.f, 0.f, 0.f, 0.f};
  f32x4 acc[4][2];
#pragma unroll
  for (int m = 0; m < 4; ++m)
#pragma unroll
    for (int j = 0; j < 2; ++j) acc[m][j] = zero;

  auto stage = [&](int buf, int kt) {
    const int k0 = kt * 64;
#pragma unroll
    for (int i = 0; i < 2; ++i) {
      unsigned idx = (unsigned)(wv * 128 + i * 64 + lane);  // 0..1023
      unsigned o = idx * 16u;
      unsigned r = o >> 7;                 // tile row (128B rows: 64 bf16)
      unsigned cb = swz<7>(o) & 127u;      // swizzled col-bytes within row
      const size_t gcol = (size_t)k0 + (cb >> 1);
      gload_lds16(X + (size_t)(brow + r) * K + gcol, &ldsA[buf][idx * 8]);
      gload_lds16(Bt + (size_t)(bcol + r) * K + gcol, &ldsB[buf][idx * 8]);
    }
  };

  stage(0, 0);
  __syncthreads();
  int buf = 0;
  const int nt = K / 64;
  for (int kt = 0; kt < nt; ++kt) {
    if (kt + 1 < nt) stage(buf ^ 1, kt + 1);
    __builtin_amdgcn_s_setprio(1);
#pragma unroll
    for (int s = 0; s < 2; ++s) {
      const unsigned kb = (unsigned)(s * 64 + g * 16);
      bf16x8 af[4], bfv[2];
#pragma unroll
      for (int m = 0; m < 4; ++m) {
        unsigned row = (unsigned)(wr * 64 + m * 16 + c);
        af[m] = *(const bf16x8*)((const char*)&ldsA[buf][0] + swz<7>(row * 128 + kb));
      }
#pragma unroll
      for (int j = 0; j < 2; ++j) {
        unsigned row = (unsigned)((wc + j * 4) * 16 + c);
        bfv[j] = *(const bf16x8*)((const char*)&ldsB[buf][0] + swz<7>(row * 128 + kb));
      }
#pragma unroll
      for (int m = 0; m < 4; ++m)
#pragma unroll
        for (int j = 0; j < 2; ++j)
          acc[m][j] = __builtin_amdgcn_mfma_f32_16x16x32_bf16(af[m], bfv[j], acc[m][j], 0, 0, 0);
    }
    __builtin_amdgcn_s_setprio(0);
    __syncthreads();
    buf ^= 1;
  }

  // epilogue: acc[m][j] -> row = brow + wr*64 + m*16 + g*4 + r,
  //           col = bcol + (wc + j*4)*16 + c ; j=0/1 are 64 cols apart (rotary pair).
  if (bz < 2) {
#pragma unroll
    for (int m = 0; m < 4; ++m) {
      const int rbase = brow + wr * 64 + m * 16 + g * 4;
#pragma unroll
      for (int r = 0; r < 4; ++r) {
        const int pos = rbase + r;
        const int i = wc * 16 + c;
        const float co = ctab[(size_t)pos * 64 + i];
        const float si = stab[(size_t)pos * 64 + i];
        u16* crow = Cp + (size_t)pos * N + bcol;
        const float x1 = acc[m][0][r], x2 = acc[m][1][r];
        crow[i] = f2bf(x1 * co - x2 * si);
        crow[i + 64] = f2bf(x2 * co + x1 * si);
      }
    }
  } else {
#pragma unroll
    for (int m = 0; m < 4; ++m) {
      const int rbase = brow + wr * 64 + m * 16 + g * 4;
#pragma unroll
      for (int r = 0; r < 4; ++r) {
        u16* crow = Cp + (size_t)(rbase + r) * N + bcol;
        crow[wc * 16 + c] = f2bf(acc[m][0][r]);
        crow[wc * 16 + 64 + c] = f2bf(acc[m][1][r]);
      }
    }
  }
}

// ---------------- out-proj GEMM: 8-wave 128x128 2-phase (R10 qkv structure, f32 out) ----------------

__global__ __launch_bounds__(512, 4) void gemm_out_kernel(
    const u16* __restrict__ Ob, const u16* __restrict__ Wot, float* __restrict__ out) {
  __shared__ u16 ldsA[2][8192];
  __shared__ u16 ldsB[2][8192];
  // 512 blocks = 8 * 64
  int flat = blockIdx.y * 16 + blockIdx.x;
  int nf = (flat & 7) * 64 + (flat >> 3);
  int bx = nf & 15, by = nf >> 4;
  const int brow = by * 128, bcol = bx * 128;

  const int tid = threadIdx.x;
  const int lane = tid & 63;
  const int wv = tid >> 6;       // 0..7
  const int wr = wv >> 2;        // 0..1
  const int wc = wv & 3;         // 0..3 : col-frags {wc, wc+4}
  const int g = lane >> 4, c = lane & 15;
  const int K = HID, N = HID;

  const f32x4 zero = {0.f, 0.f, 0.f, 0.f};
  f32x4 acc[4][2];
#pragma unroll
  for (int m = 0; m < 4; ++m)
#pragma unroll
    for (int j = 0; j < 2; ++j) acc[m][j] = zero;

  auto stage = [&](int buf, int kt) {
    const int k0 = kt * 64;
#pragma unroll
    for (int i = 0; i < 2; ++i) {
      unsigned idx = (unsigned)(wv * 128 + i * 64 + lane);
      unsigned o = idx * 16u;
      unsigned r = o >> 7;
      unsigned cb = swz<7>(o) & 127u;
      const size_t gcol = (size_t)k0 + (cb >> 1);
      gload_lds16(Ob + (size_t)(brow + r) * K + gcol, &ldsA[buf][idx * 8]);
      gload_lds16(Wot + (size_t)(bcol + r) * K + gcol, &ldsB[buf][idx * 8]);
    }
  };

  stage(0, 0);
  __syncthreads();
  int buf = 0;
  const int nt = K / 64;
  for (int kt = 0; kt < nt; ++kt) {
    if (kt + 1 < nt) stage(buf ^ 1, kt + 1);
    __builtin_amdgcn_s_setprio(1);
#pragma unroll
    for (int s = 0; s < 2; ++s) {
      const unsigned kb = (unsigned)(s * 64 + g * 16);
      bf16x8 af[4], bfv[2];
#pragma unroll
      for (int m = 0; m < 4; ++m) {
        unsigned row = (unsigned)(wr * 64 + m * 16 + c);
        af[m] = *(const bf16x8*)((const char*)&ldsA[buf][0] + swz<7>(row * 128 + kb));
      }
#pragma unroll
      for (int j = 0; j < 2; ++j) {
        unsigned row = (unsigned)((wc + j * 4) * 16 + c);
        bfv[j] = *(const bf16x8*)((const char*)&ldsB[buf][0] + swz<7>(row * 128 + kb));
      }
#pragma unroll
      for (int m = 0; m < 4; ++m)
#pragma unroll
        for (int j = 0; j < 2; ++j)
          acc[m][j] = __builtin_amdgcn_mfma_f32_16x16x32_bf16(af[m], bfv[j], acc[m][j], 0, 0, 0);
    }
    __builtin_amdgcn_s_setprio(0);
    __syncthreads();
    buf ^= 1;
  }

#pragma unroll
  for (int m = 0; m < 4; ++m) {
    const int rbase = brow + wr * 64 + m * 16 + g * 4;
#pragma unroll
    for (int r = 0; r < 4; ++r) {
      float* crow = out + (size_t)(rbase + r) * N + bcol;
      crow[wc * 16 + c] = acc[m][0][r];
      crow[wc * 16 + 64 + c] = acc[m][1][r];
    }
  }
}

// ---------------- windowed flash attention: swapped QK^T, in-register softmax ----------------
// (R7 structure; prologue merged: Q->k_lds[1] + K(t_start)->k_lds[0] + V in one barrier pair)

__global__ __launch_bounds__(256, 3) void attn_kernel(
    const u16* __restrict__ Q, const u16* __restrict__ K,
    const u16* __restrict__ V, u16* __restrict__ O) {
  __shared__ u16 k_lds[2][8192];   // [64 keys(pi-rows)][128 d] swz<8> (256B rows), dbuf 32KB
  __shared__ u16 vt_lds[8192];     // V^T [128 d][64 keys] xor-swizzled, single      16KB

  const int lane = threadIdx.x & 63;
  const int wv = threadIdx.x >> 6;
  const int g = lane >> 4;   // 0..3
  const int c = lane & 15;

  // T1: chunked swizzle so one XCD sees contiguous q-blocks of the same head
  int flat = blockIdx.y * 64 + blockIdx.x;       // 1024 = 8 * 128
  int nf = (flat & 7) * 128 + (flat >> 3);
  const int q0 = (nf & 63) * 64;
  const int h = nf >> 6;
  const int qw = q0 + wv * 16;
  const int qpos = qw + c;       // this lane's q row

  auto stageK = [&](int buf, int t0) {
#pragma unroll
    for (int i = 0; i < 4; ++i) {
      unsigned o = ((unsigned)(wv * 4 + i) * 64 + (unsigned)lane) * 16u;
      unsigned r = o >> 8;  // LDS row 0..63
      // pi-inverse: key bits [r5, r3, r2, r4, r1, r0]
      unsigned key = (r & 0x23u) | ((r & 0x0Cu) << 1) | ((r & 0x10u) >> 2);
      unsigned cb = swz<8>(o) & 255u;
      gload_lds16(K + (size_t)(t0 + (int)key) * HID + h * HD + (cb >> 1),
                  &k_lds[buf][(wv * 4 + i) * 512]);
    }
  };
  u16x8 vr[4];
  auto loadV = [&](int t0) {
    const u16x8* src = (const u16x8*)(V + (size_t)(t0 + lane) * HID + h * HD + wv * 32);
#pragma unroll
    for (int it = 0; it < 4; ++it) vr[it] = src[it];
  };
  auto writeVT = [&]() {
#pragma unroll
    for (int it = 0; it < 4; ++it)
#pragma unroll
      for (int j = 0; j < 8; ++j) {
        const int d = wv * 32 + it * 8 + j;
        vt_lds[d * 64 + (lane ^ ((d & 7) << 3))] = vr[it][j];
      }
  };

  const int t_start = (q0 >= WIN) ? (q0 - WIN) : 0;

  // ---- merged prologue: Q -> k_lds[1] (linear rows), K(t_start) -> k_lds[0], V -> regs ----
#pragma unroll
  for (int i = 0; i < 4; ++i) {
    unsigned o = ((unsigned)(wv * 4 + i) * 64 + (unsigned)lane) * 16u;
    unsigned r = o >> 8;
    unsigned cb = swz<8>(o) & 255u;
    gload_lds16(Q + (size_t)(q0 + r) * HID + h * HD + (cb >> 1), &k_lds[1][(wv * 4 + i) * 512]);
  }
  stageK(0, t_start);
  loadV(t_start);
  __syncthreads();           // Q + K in LDS, V in regs (vm drained), rendezvous

  bf16x8 qf[4];
#pragma unroll
  for (int s = 0; s < 4; ++s) {
    unsigned row = wv * 16 + c;
    qf[s] = *(const bf16x8*)((const char*)&k_lds[1][0] + swz<8>(row * 256 + s * 64 + g * 16));
  }
  writeVT();
  __syncthreads();           // qf reads retired (lgkm drain) before anyone restages buf1; VT visible

  const f32x4 zero = {0.f, 0.f, 0.f, 0.f};
  float mrow = -1e30f, lrow = 0.f;
  f32x4 oacc[8];
#pragma unroll
  for (int d = 0; d < 8; ++d) oacc[d] = zero;

  const float scale2 = 0.12751743f;  // (1/sqrt(128)) * log2(e)
  int b = 0;

  for (int t0 = t_start; t0 <= q0; t0 += 64) {
    const bool has_next = (t0 + 64 <= q0);
    if (has_next) {
      loadV(t0 + 64);        // issue V first (oldest; vmcnt(4) below waits only these)
      stageK(b ^ 1, t0 + 64);
    }

    // S^T = K Q (swapped): sa[kf] rows = key-slot g*4+r, col = q = c
    f32x4 sa[4];
#pragma unroll
    for (int kf = 0; kf < 4; ++kf) sa[kf] = zero;
    __builtin_amdgcn_s_setprio(1);
#pragma unroll
    for (int s = 0; s < 4; ++s) {
#pragma unroll
      for (int kf = 0; kf < 4; ++kf) {
        unsigned row = kf * 16 + c;
        bf16x8 kb = *(const bf16x8*)((const char*)&k_lds[b][0] + swz<8>(row * 256 + s * 64 + g * 16));
        sa[kf] = __builtin_amdgcn_mfma_f32_16x16x32_bf16(kb, qf[s], sa[kf], 0, 0, 0);
      }
    }
    __builtin_amdgcn_s_setprio(0);

    // semantic key of sa[kf][r]: t0 + (kf>>1)*32 + g*8 + (kf&1)*4 + r
    const bool diag = (t0 == q0);
    const bool lowm = (q0 >= WIN) && (t0 == t_start);
    if (diag) {
#pragma unroll
      for (int kf = 0; kf < 4; ++kf) {
        const int kbase = t0 + (kf >> 1) * 32 + g * 8 + (kf & 1) * 4;
#pragma unroll
        for (int r = 0; r < 4; ++r) {
          float x = sa[kf][r] * scale2;
          sa[kf][r] = (kbase + r <= qpos) ? x : -1e30f;
        }
      }
    } else if (lowm) {
#pragma unroll
      for (int kf = 0; kf < 4; ++kf) {
        const int kbase = t0 + (kf >> 1) * 32 + g * 8 + (kf & 1) * 4;
#pragma unroll
        for (int r = 0; r < 4; ++r) {
          float x = sa[kf][r] * scale2;
          sa[kf][r] = (kbase + r > qpos - WIN) ? x : -1e30f;
        }
      }
    } else {
#pragma unroll
      for (int kf = 0; kf < 4; ++kf)
#pragma unroll
        for (int r = 0; r < 4; ++r) sa[kf][r] *= scale2;
    }

    // row max: in-lane 16 + cross-g
    float tmax = -3e38f;
#pragma unroll
    for (int kf = 0; kf < 4; ++kf)
#pragma unroll
      for (int r = 0; r < 4; ++r) tmax = fmaxf(tmax, sa[kf][r]);
    tmax = fmaxf(tmax, __shfl_xor(tmax, 16));
    tmax = fmaxf(tmax, __shfl_xor(tmax, 32));

    // T13 defer-rescale
    if (!__all((int)(tmax <= mrow + 8.f))) {
      const float mn = fmaxf(mrow, tmax);
      const float al = exp2a(mrow - mn);
      mrow = mn;
      lrow *= al;
      float alo[4];
#pragma unroll
      for (int r = 0; r < 4; ++r) alo[r] = __shfl(al, (lane & 48) | (g * 4 + r));
#pragma unroll
      for (int df = 0; df < 8; ++df)
#pragma unroll
        for (int r = 0; r < 4; ++r) oacc[df][r] *= alo[r];
    }

    // P = exp2(S - m); row-sum
    float rs = 0.f;
    if (diag || lowm) {
#pragma unroll
      for (int kf = 0; kf < 4; ++kf)
#pragma unroll
        for (int r = 0; r < 4; ++r) {
          const float x = sa[kf][r];
          const float p = (x < -1e29f) ? 0.f : exp2a(x - mrow);
          sa[kf][r] = p; rs += p;
        }
    } else {
#pragma unroll
      for (int kf = 0; kf < 4; ++kf)
#pragma unroll
        for (int r = 0; r < 4; ++r) {
          const float p = exp2a(sa[kf][r] - mrow);
          sa[kf][r] = p; rs += p;
        }
    }
    rs += __shfl_xor(rs, 16);
    rs += __shfl_xor(rs, 32);
    lrow += rs;

    // pa from OWN registers (pi-permutation makes P lane-local in A-layout)
    union { bf16x8 v; unsigned u[4]; } pa0, pa1;
    pa0.u[0] = pk2(sa[0][0], sa[0][1]); pa0.u[1] = pk2(sa[0][2], sa[0][3]);
    pa0.u[2] = pk2(sa[1][0], sa[1][1]); pa0.u[3] = pk2(sa[1][2], sa[1][3]);
    pa1.u[0] = pk2(sa[2][0], sa[2][1]); pa1.u[1] = pk2(sa[2][2], sa[2][3]);
    pa1.u[2] = pk2(sa[3][0], sa[3][1]); pa1.u[3] = pk2(sa[3][2], sa[3][3]);

    // O += P V
    __builtin_amdgcn_s_setprio(1);
#pragma unroll
    for (int s2 = 0; s2 < 2; ++s2) {
      const bf16x8 pa = s2 ? pa1.v : pa0.v;
#pragma unroll
      for (int df = 0; df < 8; ++df) {
        const int row = df * 16 + c;
        const bf16x8 vb = *(const bf16x8*)&vt_lds[row * 64 + ((s2 * 32 + g * 8) ^ ((row & 7) << 3))];
        oacc[df] = __builtin_amdgcn_mfma_f32_16x16x32_bf16(pa, vb, oacc[df], 0, 0, 0);
      }
    }
    __builtin_amdgcn_s_setprio(0);

    // barrier1: all waves' K/VT reads retired -> safe to overwrite VT
    asm volatile("s_waitcnt lgkmcnt(0)" ::: "memory");
    __builtin_amdgcn_s_barrier();

    if (has_next) {
      asm volatile("s_waitcnt vmcnt(4)" ::: "memory");  // V regs landed (K gloads may fly)
      writeVT();
    }
    // barrier2: VT writes visible; K(t+1) landed (issued a full tile ago)
    asm volatile("s_waitcnt vmcnt(0) lgkmcnt(0)" ::: "memory");
    __builtin_amdgcn_s_barrier();
    b ^= 1;
  }

  // output: oacc[df][r] = O[qw + g*4 + r][df*16 + c]; l for that row fetched cross-lane
  float ilo[4];
  const float invl = 1.f / lrow;
#pragma unroll
  for (int r = 0; r < 4; ++r) ilo[r] = __shfl(invl, (lane & 48) | (g * 4 + r));
#pragma unroll
  for (int df = 0; df < 8; ++df)
#pragma unroll
    for (int r = 0; r < 4; ++r) {
      const int row = qw + g * 4 + r;
      const int col = h * HD + df * 16 + c;
      O[(size_t)row * HID + col] = f2bf(oacc[df][r] * ilo[r]);
    }
}

// ---------------- launch ----------------

extern "C" void kernel_launch(void* const* d_in, const int* in_sizes, int n_in,
                              void* d_out, int out_size, void* d_ws, size_t ws_size,
                              hipStream_t stream) {
  const float* hidden = (const float*)d_in[0];
  const float* wq = (const float*)d_in[1];
  const float* wk = (const float*)d_in[2];
  const float* wv = (const float*)d_in[3];
  const float* wo = (const float*)d_in[4];
  float* out = (float*)d_out;

  char* ws = (char*)d_ws;
  u16* Xb  = (u16*)ws;                 ws += (size_t)SEQ * HID * 2;
  u16* Wqt = (u16*)ws;                 ws += (size_t)HID * HID * 2;
  u16* Wkt = (u16*)ws;                 ws += (size_t)HID * HID * 2;
  u16* Wvt = (u16*)ws;                 ws += (size_t)HID * HID * 2;
  u16* Wot = (u16*)ws;                 ws += (size_t)HID * HID * 2;
  u16* Qb  = (u16*)ws;                 ws += (size_t)SEQ * HID * 2;
  u16* Kb  = (u16*)ws;                 ws += (size_t)SEQ * HID * 2;
  u16* Vb  = (u16*)ws;                 ws += (size_t)SEQ * HID * 2;
  u16* Ob  = (u16*)ws;                 ws += (size_t)SEQ * HID * 2;
  float* ctab = (float*)ws;            ws += (size_t)SEQ * 64 * 4;
  float* stab = (float*)ws;            ws += (size_t)SEQ * 64 * 4;

  dim3 gp(64, 64, 6);
  prep_kernel<<<gp, 256, 0, stream>>>(hidden, wq, wk, wv, wo, Xb, Wqt, Wkt, Wvt, Wot, ctab, stab);

  dim3 gq(HID / 128, SEQ / 128, 3);
  gemm_qkv_kernel<<<gq, 512, 0, stream>>>(Xb, Wqt, Wkt, Wvt, Qb, Kb, Vb, ctab, stab);

  dim3 ga(SEQ / 64, NH);
  attn_kernel<<<ga, 256, 0, stream>>>(Qb, Kb, Vb, Ob);

  dim3 go(HID / 128, SEQ / 128);
  gemm_out_kernel<<<go, 512, 0, stream>>>(Ob, Wot, out);
}